// Round 17
// baseline (503.456 us; speedup 1.0000x reference)
//
#include <hip/hip_runtime.h>
#include <hip/hip_bf16.h>
#include <stdint.h>

#define Bb 2
#define Ss 2048
#define Hh 4096
#define NHh 32
#define HDd 128
#define KVHh 2

typedef __attribute__((ext_vector_type(8))) short bf16x8;
typedef __attribute__((ext_vector_type(4))) float f32x4;
typedef __attribute__((ext_vector_type(16))) float f32x16;
typedef __attribute__((ext_vector_type(4))) unsigned int u32x4;
typedef unsigned short u16;
typedef unsigned int u32;
typedef unsigned long long u64;

__device__ __forceinline__ u16 f2b(float f) {
  union { float f; u32 u; } v; v.f = f;
  u32 r = v.u + 0x7fffu + ((v.u >> 16) & 1u);
  return (u16)(r >> 16);
}
__device__ __forceinline__ float b2f(u16 h) {
  union { u32 u; float f; } v; v.u = ((u32)h) << 16;
  return v.f;
}

__device__ __forceinline__ u32 cvtpk(float lo, float hi_) {
  u32 r;
  asm("v_cvt_pk_bf16_f32 %0, %1, %2" : "=v"(r) : "v"(lo), "v"(hi_));
  return r;
}
__device__ __forceinline__ void plswap(u32& x, u32& y) {
  asm volatile("v_permlane32_swap_b32 %0, %1" : "+v"(x), "+v"(y));
}

// async global->LDS, 16B per lane; LDS dest is wave-uniform base + lane*16
__device__ __forceinline__ void gload_lds16(const u16* g, u16* l) {
  __builtin_amdgcn_global_load_lds(
      (const __attribute__((address_space(1))) u32*)(uintptr_t)g,
      (__attribute__((address_space(3))) u32*)(u32)(uintptr_t)l,
      16, 0, 0);
}

// ---------------- fused f32 -> bf16 convert: hidden + Wqkv ----------------
__global__ void cvt2_k(const float* __restrict__ a, u16* __restrict__ oa,
                       const float* __restrict__ b, u16* __restrict__ ob) {
  int i = blockIdx.x * blockDim.x + threadIdx.x;
  const float* src;
  u16* dst;
  int off;
  if (i < 4194304) { src = a; dst = oa; off = i; }
  else { src = b; dst = ob; off = i - 4194304; }
  int idx = off * 4;
  float4 v = *(const float4*)&src[idx];
  u64 pack = (u64)f2b(v.x) | ((u64)f2b(v.y) << 16) |
             ((u64)f2b(v.z) << 32) | ((u64)f2b(v.w) << 48);
  *(u64*)&dst[idx] = pack;
}

// ---------------- f32 -> bf16 convert (Wdense, after QKV GEMM) ----------
__global__ void cvtW_k(const float* __restrict__ in, u16* __restrict__ out) {
  int i = blockIdx.x * blockDim.x + threadIdx.x;
  int idx = i * 4;
  float4 v = *(const float4*)&in[idx];
  u64 pack = (u64)f2b(v.x) | ((u64)f2b(v.y) << 16) |
             ((u64)f2b(v.z) << 32) | ((u64)f2b(v.w) << 48);
  *(u64*)&out[idx] = pack;
}

// ---------------- RoPE in-place on (B, nheads, S, HD) bf16 — K only ----------------
__global__ void rope_k(u16* __restrict__ X, const float* __restrict__ rope, int nheads) {
  int i = blockIdx.x * blockDim.x + threadIdx.x;
  int p = i & 31;
  int s = (i >> 5) & (Ss - 1);
  int bh = i >> 16;
  if (bh >= Bb * nheads) return;
  int b = bh / nheads;
  size_t base = ((size_t)bh * Ss + s) * HDd + p * 2;
  u32 x01 = *(u32*)&X[base];
  float x0 = b2f((u16)(x01 & 0xffff));
  float x1 = b2f((u16)(x01 >> 16));
  float2 rc = *(const float2*)&rope[(((size_t)b * Ss + s) * 32 + p) * 2];
  float o0 = x0 * rc.x - x1 * rc.y;
  float o1 = x1 * rc.x + x0 * rc.y;
  u32 o = (u32)f2b(o0) | ((u32)f2b(o1) << 16);
  *(u32*)&X[base] = o;
}

// ---------------- QKV GEMM: 256x128 tile, BK=32, counted-vmcnt dbuf ----------------
// R8-proven staging/sync; inner math switched to 32x32x16 MFMA (2382 vs 2075 TF
// ceiling, ~18% less MFMA-pipe time at equal FLOPs). Fragment layouts identical to
// the attn kernel's verified usage: A/B lane = row(l&31) + half-K(l>>5);
// C/D: col = lane&31 (B-row = n), row-in-regs = (r&3)+8(r>>2)+4*hi (A-row = m).
template <int KK>
__device__ __forceinline__ void stage_tileA(const u16* __restrict__ gbase, u16* dst, int tid) {
#pragma unroll
  for (int li = 0; li < 2; ++li) {
    int t16 = li * 512 + tid;
    int rt = t16 >> 2, ct = t16 & 3;
    int cg = ct ^ ((rt >> 1) & 3);
    gload_lds16(gbase + (size_t)rt * KK + cg * 8, dst + t16 * 8);
  }
}
template <int KK>
__device__ __forceinline__ void stage_tileB(const u16* __restrict__ gbase, u16* dst, int tid) {
  int t16 = tid;
  int rt = t16 >> 2, ct = t16 & 3;
  int cg = ct ^ ((rt >> 1) & 3);
  gload_lds16(gbase + (size_t)rt * KK + cg * 8, dst + t16 * 8);
}

// read 8 bf16 (16B) at [row][chunk*8] of a [*][32]-elem LDS tile, chunk 0..3 swizzled
__device__ __forceinline__ bf16x8 frag32(const u16* buf, int row, int chunk) {
  int ch = chunk ^ ((row >> 1) & 3);
  return *(const bf16x8*)&buf[row * 32 + ch * 8];
}

template <int NN, int KK, int COLG>
__global__ __launch_bounds__(512, 4) void gemm_qkv(
    const u16* __restrict__ A, const u16* __restrict__ Bm,
    const float* __restrict__ bias,
    u16* __restrict__ Qb, u16* __restrict__ Kb, u16* __restrict__ Vb) {
  __shared__ u16 As[2][8192];
  __shared__ u16 Bs[2][4096];
  const int tid = threadIdx.x;
  const int wave = tid >> 6;
  const int lane = tid & 63;
  const int l31 = lane & 31;
  const int hi = lane >> 5;
  const int wr = wave >> 1;
  const int wc = wave & 1;
  const int bid = blockIdx.x;
  const int xcd = bid & 7;
  const int local = bid >> 3;
  const int rlr = local / COLG;
  const int rlc = local - rlr * COLG;
  const int m0 = ((xcd >> 2) * 8 + rlr) * 256;
  const int n0 = ((xcd & 3) * COLG + rlc) * 128;
  const int NT = KK / 32;

  f32x16 acc[2][2];
#pragma unroll
  for (int i = 0; i < 2; ++i)
#pragma unroll
    for (int j = 0; j < 2; ++j)
#pragma unroll
      for (int r = 0; r < 16; ++r) acc[i][j][r] = 0.f;

  const u16* Ab = A + (size_t)m0 * KK;
  const u16* Bw = Bm + (size_t)n0 * KK;

  stage_tileA<KK>(Ab, &As[0][0], tid);
  stage_tileB<KK>(Bw, &Bs[0][0], tid);
  asm volatile("s_waitcnt vmcnt(0)");
  __syncthreads();

  int cur = 0;
  for (int t = 0; t < NT; ++t) {
    if (t + 1 < NT) {
      stage_tileA<KK>(Ab + (t + 1) * 32, &As[cur ^ 1][0], tid);
      stage_tileB<KK>(Bw + (t + 1) * 32, &Bs[cur ^ 1][0], tid);
      asm volatile("s_waitcnt vmcnt(3)");
    } else {
      asm volatile("s_waitcnt vmcnt(0)");
    }
    __builtin_amdgcn_s_barrier();
    __builtin_amdgcn_sched_barrier(0);

    bf16x8 af[2][2], bf[2][2];   // [mi2|ni2][kk]
#pragma unroll
    for (int mi2 = 0; mi2 < 2; ++mi2)
#pragma unroll
      for (int kk = 0; kk < 2; ++kk)
        af[mi2][kk] = frag32(&As[cur][0], wr * 64 + mi2 * 32 + l31, kk * 2 + hi);
#pragma unroll
    for (int ni2 = 0; ni2 < 2; ++ni2)
#pragma unroll
      for (int kk = 0; kk < 2; ++kk)
        bf[ni2][kk] = frag32(&Bs[cur][0], wc * 64 + ni2 * 32 + l31, kk * 2 + hi);
    asm volatile("s_waitcnt lgkmcnt(0)");
    __builtin_amdgcn_sched_barrier(0);
    __builtin_amdgcn_s_setprio(1);
#pragma unroll
    for (int mi2 = 0; mi2 < 2; ++mi2)
#pragma unroll
      for (int ni2 = 0; ni2 < 2; ++ni2)
#pragma unroll
        for (int kk = 0; kk < 2; ++kk)
          acc[mi2][ni2] = __builtin_amdgcn_mfma_f32_32x32x16_bf16(af[mi2][kk], bf[ni2][kk], acc[mi2][ni2], 0, 0, 0);
    __builtin_amdgcn_s_setprio(0);
    __builtin_amdgcn_s_barrier();
    cur ^= 1;
  }

  // epilogue: bias + Q/K/V scatter; n is per-lane constant within each ni2
#pragma unroll
  for (int ni2 = 0; ni2 < 2; ++ni2) {
    int n = n0 + wc * 64 + ni2 * 32 + l31;
    float bv = bias[n];
#pragma unroll
    for (int mi2 = 0; mi2 < 2; ++mi2) {
#pragma unroll
      for (int r = 0; r < 16; ++r) {
        int m = m0 + wr * 64 + mi2 * 32 + (r & 3) + 8 * (r >> 2) + 4 * hi;
        int bb = m >> 11;
        int ss = m & 2047;
        u16 hv = f2b(acc[mi2][ni2][r] + bv);
        if (n < 4096) {
          Qb[(((size_t)bb * NHh + (n >> 7)) * Ss + ss) * HDd + (n & 127)] = hv;
        } else if (n < 4352) {
          int idx2 = n - 4096;
          Kb[(((size_t)bb * KVHh + (idx2 >> 7)) * Ss + ss) * HDd + (idx2 & 127)] = hv;
        } else {
          int idx2 = n - 4352;
          Vb[(((size_t)bb * KVHh + (idx2 >> 7)) * Ss + ss) * HDd + (idx2 & 127)] = hv;
        }
      }
    }
  }
}

// ---------------- dense GEMM: 256x256 tile, 4-quadrant schedule, 32x32x16 MFMA ------
// R15-proven staging/sync (A-dbuf kt+1 in P0/P1, B two-ahead in P2/P3, vmcnt(4)).
// Inner math now 32x32x16: per phase 8 MFMA (64 cyc) instead of 16x16x32's 78.
__global__ __launch_bounds__(512, 2) void gemm_d256(
    const u16* __restrict__ A, const u16* __restrict__ Bm,
    float* __restrict__ Cout) {
  __shared__ u16 SM[2][4][8192];    // [buf][Bh0,Bh1,Ah0,Ah1][128x64 bf16]
  const int tid = threadIdx.x;
  const int wave = tid >> 6;
  const int lane = tid & 63;
  const int l31 = lane & 31;
  const int hi = lane >> 5;
  const int wr = wave >> 2;          // 0..1 (M half)
  const int wc = wave & 3;           // 0..3 (N quarter)
  const int bid = blockIdx.x;
  const int xcd = bid & 7;
  const int local = bid >> 3;
  const int m0 = ((xcd >> 2) * 8 + (local >> 2)) * 256;
  const int n0 = ((xcd & 3) * 4 + (local & 3)) * 256;
  const int NT = 64;

  f32x16 acc[4][2];                  // [mi2 0..3 over 128 rows][ni2 0..1 over 64 cols]
#pragma unroll
  for (int i = 0; i < 4; ++i)
#pragma unroll
    for (int j = 0; j < 2; ++j)
#pragma unroll
      for (int r = 0; r < 16; ++r) acc[i][j][r] = 0.f;

  auto stage_half = [&](const u16* grows, int j, u16* dst) {
    if (j >= NT) return;
#pragma unroll
    for (int li = 0; li < 2; ++li) {
      int t16 = li * 512 + tid;
      int row = t16 >> 3, c = t16 & 7;
      int cs = c ^ (row & 7);
      gload_lds16(grows + (size_t)row * 4096 + j * 64 + cs * 8, dst + t16 * 8);
    }
  };
  const u16* Ah0g = A + (size_t)m0 * 4096;
  const u16* Ah1g = A + (size_t)(m0 + 128) * 4096;
  const u16* Bh0g = Bm + (size_t)n0 * 4096;
  const u16* Bh1g = Bm + (size_t)(n0 + 128) * 4096;

  stage_half(Ah0g, 0, &SM[0][2][0]);
  stage_half(Ah1g, 0, &SM[0][3][0]);
  stage_half(Bh0g, 0, &SM[0][0][0]);
  stage_half(Bh1g, 0, &SM[0][1][0]);
  stage_half(Bh0g, 1, &SM[1][0][0]);
  stage_half(Bh1g, 1, &SM[1][1][0]);
  asm volatile("s_waitcnt vmcnt(0)");
  __builtin_amdgcn_s_barrier();
  __builtin_amdgcn_sched_barrier(0);

  for (int kt = 0; kt < NT; ++kt) {
    const int cur = kt & 1;
    const int nxt = cur ^ 1;
    const u16* Ahl = &SM[cur][2 + wr][0];
    const u16* Bhl = &SM[cur][wc >> 1][0];
    const int rB0 = (wc & 1) * 64;
    // [row][64-elem] tile, 8 chunks of 8; chunk = kk*2+hi (kk 0..3), swz ch = chunk^(r&7)
    auto rdA = [&](int r, int kk) {
      int ch = (kk * 2 + hi) ^ (r & 7);
      return *(const bf16x8*)&Ahl[r * 64 + ch * 8];
    };
    auto rdB = [&](int r, int kk) {
      int ch = (kk * 2 + hi) ^ (r & 7);
      return *(const bf16x8*)&Bhl[r * 64 + ch * 8];
    };

    bf16x8 bfr[2][4], af[4];
    // ---- P0: read B all (8) + A mi2=0 (4); stage A(kt+1) h0 ----
#pragma unroll
    for (int ni2 = 0; ni2 < 2; ++ni2)
#pragma unroll
      for (int kk = 0; kk < 4; ++kk)
        bfr[ni2][kk] = rdB(rB0 + ni2 * 32 + l31, kk);
#pragma unroll
    for (int kk = 0; kk < 4; ++kk)
      af[kk] = rdA(0 * 32 + l31, kk);
    stage_half(Ah0g, kt + 1, &SM[nxt][2][0]);
    __builtin_amdgcn_s_barrier();
    asm volatile("s_waitcnt lgkmcnt(0)");
    __builtin_amdgcn_sched_barrier(0);
    __builtin_amdgcn_s_setprio(1);
#pragma unroll
    for (int ni2 = 0; ni2 < 2; ++ni2)
#pragma unroll
      for (int kk = 0; kk < 4; ++kk)
        acc[0][ni2] = __builtin_amdgcn_mfma_f32_32x32x16_bf16(af[kk], bfr[ni2][kk], acc[0][ni2], 0, 0, 0);
    __builtin_amdgcn_s_setprio(0);
    __builtin_amdgcn_s_barrier();

    // ---- P1: read A mi2=1; stage A(kt+1) h1 ----
#pragma unroll
    for (int kk = 0; kk < 4; ++kk)
      af[kk] = rdA(1 * 32 + l31, kk);
    stage_half(Ah1g, kt + 1, &SM[nxt][3][0]);
    __builtin_amdgcn_s_barrier();
    asm volatile("s_waitcnt lgkmcnt(0)");
    __builtin_amdgcn_sched_barrier(0);
    __builtin_amdgcn_s_setprio(1);
#pragma unroll
    for (int ni2 = 0; ni2 < 2; ++ni2)
#pragma unroll
      for (int kk = 0; kk < 4; ++kk)
        acc[1][ni2] = __builtin_amdgcn_mfma_f32_32x32x16_bf16(af[kk], bfr[ni2][kk], acc[1][ni2], 0, 0, 0);
    __builtin_amdgcn_s_setprio(0);
    __builtin_amdgcn_s_barrier();

    // ---- P2: read A mi2=2; stage B(kt+2) h0 (B reads done in P0) ----
#pragma unroll
    for (int kk = 0; kk < 4; ++kk)
      af[kk] = rdA(2 * 32 + l31, kk);
    stage_half(Bh0g, kt + 2, &SM[cur][0][0]);
    __builtin_amdgcn_s_barrier();
    asm volatile("s_waitcnt lgkmcnt(0)");
    __builtin_amdgcn_sched_barrier(0);
    __builtin_amdgcn_s_setprio(1);
#pragma unroll
    for (int ni2 = 0; ni2 < 2; ++ni2)
#pragma unroll
      for (int kk = 0; kk < 4; ++kk)
        acc[2][ni2] = __builtin_amdgcn_mfma_f32_32x32x16_bf16(af[kk], bfr[ni2][kk], acc[2][ni2], 0, 0, 0);
    __builtin_amdgcn_s_setprio(0);
    __builtin_amdgcn_s_barrier();

    // ---- P3: read A mi2=3; stage B(kt+2) h1; boundary vmcnt ----
#pragma unroll
    for (int kk = 0; kk < 4; ++kk)
      af[kk] = rdA(3 * 32 + l31, kk);
    stage_half(Bh1g, kt + 2, &SM[cur][1][0]);
    __builtin_amdgcn_s_barrier();
    asm volatile("s_waitcnt lgkmcnt(0)");
    __builtin_amdgcn_sched_barrier(0);
    __builtin_amdgcn_s_setprio(1);
#pragma unroll
    for (int ni2 = 0; ni2 < 2; ++ni2)
#pragma unroll
      for (int kk = 0; kk < 4; ++kk)
        acc[3][ni2] = __builtin_amdgcn_mfma_f32_32x32x16_bf16(af[kk], bfr[ni2][kk], acc[3][ni2], 0, 0, 0);
    __builtin_amdgcn_s_setprio(0);
    if (kt < NT - 2) {
      asm volatile("s_waitcnt vmcnt(4)");
    } else {
      asm volatile("s_waitcnt vmcnt(0)");
    }
    __builtin_amdgcn_s_barrier();
    __builtin_amdgcn_sched_barrier(0);
  }

  // epilogue: plain f32 store; col per-lane constant, rows from reg index
#pragma unroll
  for (int mi2 = 0; mi2 < 4; ++mi2)
#pragma unroll
    for (int ni2 = 0; ni2 < 2; ++ni2) {
      int col = n0 + wc * 64 + ni2 * 32 + l31;
#pragma unroll
      for (int r = 0; r < 16; ++r) {
        int row = m0 + wr * 128 + mi2 * 32 + (r & 3) + 8 * (r >> 2) + 4 * hi;
        Cout[(size_t)row * 4096 + col] = acc[mi2][ni2][r];
      }
    }
}

// ---------------- causal GQA flash attention, 8-wave 32x32 swapped-QK^T ----------------
__global__ __launch_bounds__(512, 2) void attn_k(
    const u16* __restrict__ Qb, const u16* __restrict__ Kb,
    const u16* __restrict__ Vb, const float* __restrict__ rope,
    u16* __restrict__ Ctx) {
  __shared__ u16 Kt[2][64 * 128];
  __shared__ u16 Vt[2][128 * 64];
  const int tid = threadIdx.x;
  const int w = tid >> 6;
  const int lane = tid & 63;
  const int l31 = lane & 31;
  const int hi = lane >> 5;
  const int h = blockIdx.y, b = blockIdx.z;
  const int hkv = h >> 4;
  const u16* Qp = Qb + ((size_t)(b * NHh + h)) * Ss * HDd;
  const u16* Kp = Kb + ((size_t)(b * KVHh + hkv)) * Ss * HDd;
  const u16* Vp = Vb + ((size_t)(b * KVHh + hkv)) * Ss * HDd;

  const float scale = 0.08838834764831845f;
  const float L2E = 1.4426950408889634f;

  for (int hp = 0; hp < 2; ++hp) {
    const int qt = hp == 0 ? (7 - (int)blockIdx.x) : (int)blockIdx.x;
    const int qs = qt * 256;
    const int qw = qs + w * 32;
    const int qrow = qw + l31;
    const int nt = qs / 64 + 4;

    bf16x8 qf[8];
#pragma unroll
    for (int ds = 0; ds < 8; ++ds)
      qf[ds] = *(const bf16x8*)&Qp[(size_t)qrow * HDd + ds * 16 + hi * 8];
#pragma unroll
    for (int ds = 0; ds < 4; ++ds) {
      bf16x8 q = qf[ds];
      bf16x8 o;
#pragma unroll
      for (int i = 0; i < 4; ++i) {
        int p = ds * 8 + hi * 4 + i;
        float2 rc = *(const float2*)&rope[(((size_t)b * Ss + qrow) * 32 + p) * 2];
        float x0 = b2f((u16)q[2 * i]), x1 = b2f((u16)q[2 * i + 1]);
        o[2 * i] = (short)f2b(x0 * rc.x - x1 * rc.y);
        o[2 * i + 1] = (short)f2b(x1 * rc.x + x0 * rc.y);
      }
      qf[ds] = o;
    }

    f32x16 accO[4];
#pragma unroll
    for (int i = 0; i < 4; ++i)
#pragma unroll
      for (int r = 0; r < 16; ++r) accO[i][r] = 0.f;
    float m_r = -3.0e38f, l_r = 0.f;

    {
#pragma unroll
      for (int i = 0; i < 2; ++i) {
        int slot = w * 2 + i;
        int r = slot * 4 + (lane >> 4);
        int p = lane & 15;
        int gc = (p & 8) | ((p ^ r) & 7);
        gload_lds16(Kp + (size_t)r * HDd + gc * 8, &Kt[0][slot * 512]);
      }
      bf16x8 v0 = *(const bf16x8*)&Vp[(size_t)lane * HDd + w * 16];
      bf16x8 v1 = *(const bf16x8*)&Vp[(size_t)lane * HDd + w * 16 + 8];
      u32x4 sv = __builtin_bit_cast(u32x4, (lane & 1) ? v0 : v1);
      u32x4 rv;
      rv.x = __shfl_xor(sv.x, 1); rv.y = __shfl_xor(sv.y, 1);
      rv.z = __shfl_xor(sv.z, 1); rv.w = __shfl_xor(sv.w, 1);
      bf16x8 recv = __builtin_bit_cast(bf16x8, rv);
      int kvp = lane >> 1;
#pragma unroll
      for (int i = 0; i < 8; ++i) {
        int d = w * 16 + (lane & 1) * 8 + i;
        u16 lo = (lane & 1) ? (u16)recv[i] : (u16)v0[i];
        u16 hb = (lane & 1) ? (u16)v1[i] : (u16)recv[i];
        u32 val = (u32)lo | ((u32)hb << 16);
        int cp = (kvp >> 2) ^ (d & 7);
        *(u32*)&Vt[0][d * 64 + cp * 8 + (kvp & 3) * 2] = val;
      }
    }
    __syncthreads();

    for (int t = 0; t < nt; ++t) {
      const int j0 = t * 64;
      const int cur = t & 1;
      const bool havenext = (t + 1 < nt);
      bf16x8 nv0, nv1;
      if (havenext) {
        const int j1 = j0 + 64;
#pragma unroll
        for (int i = 0; i < 2; ++i) {
          int slot = w * 2 + i;
          int r = slot * 4 + (lane >> 4);
          int p = lane & 15;
          int gc = (p & 8) | ((p ^ r) & 7);
          gload_lds16(Kp + (size_t)(j1 + r) * HDd + gc * 8, &Kt[cur ^ 1][slot * 512]);
        }
        nv0 = *(const bf16x8*)&Vp[(size_t)(j1 + lane) * HDd + w * 16];
        nv1 = *(const bf16x8*)&Vp[(size_t)(j1 + lane) * HDd + w * 16 + 8];
      }

      if (j0 <= qw + 31) {
        f32x16 aS[2];
#pragma unroll
        for (int a = 0; a < 2; ++a)
#pragma unroll
          for (int r = 0; r < 16; ++r) aS[a][r] = 0.f;
#pragma unroll
        for (int kvb = 0; kvb < 2; ++kvb) {
          int r = kvb * 32 + l31;
#pragma unroll
          for (int ds = 0; ds < 8; ++ds) {
            int c = ds * 2 + hi;
            int cp = (c & 8) | ((c ^ r) & 7);
            bf16x8 kf = *(const bf16x8*)&Kt[cur][r * 128 + cp * 8];
            aS[kvb] = __builtin_amdgcn_mfma_f32_32x32x16_bf16(kf, qf[ds], aS[kvb], 0, 0, 0);
          }
        }
        const bool needmask = (j0 + 63 > qw);
        float mx = -3.0e38f;
#pragma unroll
        for (int a = 0; a < 2; ++a)
#pragma unroll
          for (int r = 0; r < 16; ++r) {
            float s = aS[a][r] * scale;
            if (needmask) {
              int kv = j0 + a * 32 + (r & 3) + 8 * (r >> 2) + 4 * hi;
              s = (kv > qrow) ? -3.0e38f : s;
            }
            aS[a][r] = s;
            mx = fmaxf(mx, s);
          }
        mx = fmaxf(mx, __shfl_xor(mx, 32));
        if (!__all(mx - m_r <= 8.0f)) {
          float mnew = fmaxf(m_r, mx);
          float corr = __builtin_amdgcn_exp2f((m_r - mnew) * L2E);
          l_r *= corr;
#pragma unroll
          for (int i = 0; i < 4; ++i)
#pragma unroll
            for (int r = 0; r < 16; ++r) accO[i][r] *= corr;
          m_r = mnew;
        }
        float sum = 0.f;
#pragma unroll
        for (int a = 0; a < 2; ++a)
#pragma unroll
          for (int r = 0; r < 16; ++r) {
            float pe = __builtin_amdgcn_exp2f((aS[a][r] - m_r) * L2E);
            aS[a][r] = pe;
            sum += pe;
          }
        sum += __shfl_xor(sum, 32);
        l_r += sum;

        u32 cc0[2][4], cc1[2][4];
#pragma unroll
        for (int a = 0; a < 2; ++a)
#pragma unroll
          for (int g = 0; g < 4; ++g) {
            cc0[a][g] = cvtpk(aS[a][g * 4 + 0], aS[a][g * 4 + 1]);
            cc1[a][g] = cvtpk(aS[a][g * 4 + 2], aS[a][g * 4 + 3]);
          }
        bf16x8 pa[4];
#pragma unroll
        for (int ks = 0; ks < 4; ++ks) {
          int a = ks >> 1, g0 = (ks & 1) * 2;
          u32 w0 = cc0[a][g0], w2 = cc0[a][g0 + 1];
          u32 w1 = cc1[a][g0], w3 = cc1[a][g0 + 1];
          plswap(w0, w2);
          plswap(w1, w3);
          u32x4 tv; tv.x = w0; tv.y = w1; tv.z = w2; tv.w = w3;
          pa[ks] = __builtin_bit_cast(bf16x8, tv);
        }
#pragma unroll
        for (int dblk = 0; dblk < 4; ++dblk) {
          int d = dblk * 32 + l31;
#pragma unroll
          for (int ks = 0; ks < 4; ++ks) {
            int c = ks * 2 + hi;
            int cp = c ^ (d & 7);
            bf16x8 vf = *(const bf16x8*)&Vt[cur][d * 64 + cp * 8];
            accO[dblk] = __builtin_amdgcn_mfma_f32_32x32x16_bf16(vf, pa[ks], accO[dblk], 0, 0, 0);
          }
        }
      }

      if (havenext) {
        u32x4 sv = __builtin_bit_cast(u32x4, (lane & 1) ? nv0 : nv1);
        u32x4 rv;
        rv.x = __shfl_xor(sv.x, 1); rv.y = __shfl_xor(sv.y, 1);
        rv.z = __shfl_xor(sv.z, 1); rv.w = __shfl_xor(sv.w, 1);
        bf16x8 recv = __builtin_bit_cast(bf16x8, rv);
        int kvp = lane >> 1;
#pragma unroll
        for (int i = 0; i < 8; ++i) {
          int d = w * 16 + (lane & 1) * 8 + i;
          u16 lo = (lane & 1) ? (u16)recv[i] : (u16)nv0[i];
          u16 hb = (lane & 1) ? (u16)nv1[i] : (u16)recv[i];
          u32 val = (u32)lo | ((u32)hb << 16);
          int cp = (kvp >> 2) ^ (d & 7);
          *(u32*)&Vt[cur ^ 1][d * 64 + cp * 8 + (kvp & 3) * 2] = val;
        }
      }
      __syncthreads();
    }

    {
      float il = 1.0f / l_r;
      size_t rb = ((size_t)b * Ss + qrow) * (size_t)(NHh * HDd) + (size_t)h * HDd;
#pragma unroll
      for (int dblk = 0; dblk < 4; ++dblk)
#pragma unroll
        for (int g = 0; g < 4; ++g) {
          int d0 = dblk * 32 + g * 8 + hi * 4;
          u64 pack = (u64)f2b(accO[dblk][g * 4 + 0] * il) |
                     ((u64)f2b(accO[dblk][g * 4 + 1] * il) << 16) |
                     ((u64)f2b(accO[dblk][g * 4 + 2] * il) << 32) |
                     ((u64)f2b(accO[dblk][g * 4 + 3] * il) << 48);
          *(u64*)&Ctx[rb + d0] = pack;
        }
    }
    __syncthreads();
  }
}

extern "C" void kernel_launch(void* const* d_in, const int* in_sizes, int n_in,
                              void* d_out, int out_size, void* d_ws, size_t ws_size,
                              hipStream_t stream) {
  const float* hidden = (const float*)d_in[0];
  const float* rope = (const float*)d_in[1];
  const float* Wqkv = (const float*)d_in[3];
  const float* bqkv = (const float*)d_in[4];
  const float* Wdense = (const float*)d_in[5];
  float* out = (float*)d_out;

  // ws layout: 104 MB total (L3-friendly).
  char* w = (char*)d_ws;
  u16* Xbf = (u16*)w;
  u16* ctx = Xbf;
  w += (size_t)33554432;
  u16* Wq = (u16*)w;
  u16* Wd = Wq;                        // alias: written AFTER QKV GEMM consumed Wq
  w += (size_t)37748736;
  u16* Qb = (u16*)w; w += (size_t)33554432;
  u16* Kb = (u16*)w; w += (size_t)2097152;
  u16* Vb = (u16*)w; w += (size_t)2097152;

  // 1. fused convert: hidden->Xbf, Wqkv->Wq
  cvt2_k<<<34816, 256, 0, stream>>>(hidden, Xbf, Wqkv, Wq);
  // 2. QKV GEMM: 576 blocks; regions 8x9 per XCD
  gemm_qkv<4608, 4096, 9><<<dim3(576), 512, 0, stream>>>(
      Xbf, Wq, bqkv, Qb, Kb, Vb);
  // 3. RoPE on K only (Q's rope fused into attn_k)
  rope_k<<<(Bb * KVHh * Ss * 32 + 255) / 256, 256, 0, stream>>>(Kb, rope, KVHh);
  // 4. convert Wdense into Wq's region
  cvtW_k<<<16384, 256, 0, stream>>>(Wdense, Wd);
  // 5. flash attention (balanced causal pairing, fused Q-RoPE)
  attn_k<<<dim3(4, NHh, Bb), 512, 0, stream>>>(Qb, Kb, Vb, rope, ctx);
  // 6. dense GEMM: 256^2 4-quadrant schedule, 32x32x16 MFMA; 256 blocks (1/CU)
  gemm_d256<<<dim3(256), 512, 0, stream>>>(ctx, Wd, out);
}

// Round 18
// 487.764 us; speedup vs baseline: 1.0322x; 1.0322x over previous
//
#include <hip/hip_runtime.h>
#include <hip/hip_bf16.h>
#include <stdint.h>

#define Bb 2
#define Ss 2048
#define Hh 4096
#define NHh 32
#define HDd 128
#define KVHh 2

typedef __attribute__((ext_vector_type(8))) short bf16x8;
typedef __attribute__((ext_vector_type(4))) float f32x4;
typedef __attribute__((ext_vector_type(16))) float f32x16;
typedef __attribute__((ext_vector_type(4))) unsigned int u32x4;
typedef unsigned short u16;
typedef unsigned int u32;
typedef unsigned long long u64;

__device__ __forceinline__ u16 f2b(float f) {
  union { float f; u32 u; } v; v.f = f;
  u32 r = v.u + 0x7fffu + ((v.u >> 16) & 1u);
  return (u16)(r >> 16);
}
__device__ __forceinline__ float b2f(u16 h) {
  union { u32 u; float f; } v; v.u = ((u32)h) << 16;
  return v.f;
}

__device__ __forceinline__ u32 cvtpk(float lo, float hi_) {
  u32 r;
  asm("v_cvt_pk_bf16_f32 %0, %1, %2" : "=v"(r) : "v"(lo), "v"(hi_));
  return r;
}
__device__ __forceinline__ void plswap(u32& x, u32& y) {
  asm volatile("v_permlane32_swap_b32 %0, %1" : "+v"(x), "+v"(y));
}

// async global->LDS, 16B per lane; LDS dest is wave-uniform base + lane*16
__device__ __forceinline__ void gload_lds16(const u16* g, u16* l) {
  __builtin_amdgcn_global_load_lds(
      (const __attribute__((address_space(1))) u32*)(uintptr_t)g,
      (__attribute__((address_space(3))) u32*)(u32)(uintptr_t)l,
      16, 0, 0);
}

// ---------------- fused f32 -> bf16 convert: hidden + Wqkv ----------------
__global__ void cvt2_k(const float* __restrict__ a, u16* __restrict__ oa,
                       const float* __restrict__ b, u16* __restrict__ ob) {
  int i = blockIdx.x * blockDim.x + threadIdx.x;
  const float* src;
  u16* dst;
  int off;
  if (i < 4194304) { src = a; dst = oa; off = i; }
  else { src = b; dst = ob; off = i - 4194304; }
  int idx = off * 4;
  float4 v = *(const float4*)&src[idx];
  u64 pack = (u64)f2b(v.x) | ((u64)f2b(v.y) << 16) |
             ((u64)f2b(v.z) << 32) | ((u64)f2b(v.w) << 48);
  *(u64*)&dst[idx] = pack;
}

// ---------------- f32 -> bf16 convert (Wdense, after QKV GEMM) ----------
__global__ void cvtW_k(const float* __restrict__ in, u16* __restrict__ out) {
  int i = blockIdx.x * blockDim.x + threadIdx.x;
  int idx = i * 4;
  float4 v = *(const float4*)&in[idx];
  u64 pack = (u64)f2b(v.x) | ((u64)f2b(v.y) << 16) |
             ((u64)f2b(v.z) << 32) | ((u64)f2b(v.w) << 48);
  *(u64*)&out[idx] = pack;
}

// ---------------- RoPE in-place on (B, nheads, S, HD) bf16 — K only ----------------
__global__ void rope_k(u16* __restrict__ X, const float* __restrict__ rope, int nheads) {
  int i = blockIdx.x * blockDim.x + threadIdx.x;
  int p = i & 31;
  int s = (i >> 5) & (Ss - 1);
  int bh = i >> 16;
  if (bh >= Bb * nheads) return;
  int b = bh / nheads;
  size_t base = ((size_t)bh * Ss + s) * HDd + p * 2;
  u32 x01 = *(u32*)&X[base];
  float x0 = b2f((u16)(x01 & 0xffff));
  float x1 = b2f((u16)(x01 >> 16));
  float2 rc = *(const float2*)&rope[(((size_t)b * Ss + s) * 32 + p) * 2];
  float o0 = x0 * rc.x - x1 * rc.y;
  float o1 = x1 * rc.x + x0 * rc.y;
  u32 o = (u32)f2b(o0) | ((u32)f2b(o1) << 16);
  *(u32*)&X[base] = o;
}

// ---------------- QKV GEMM: 256x128 tile, BK=32, counted-vmcnt dbuf, 32x32x16 -------
// (R17 A/B: QKV with 32x32x16 measured faster than 16x16x32 — kept.)
template <int KK>
__device__ __forceinline__ void stage_tileA(const u16* __restrict__ gbase, u16* dst, int tid) {
#pragma unroll
  for (int li = 0; li < 2; ++li) {
    int t16 = li * 512 + tid;
    int rt = t16 >> 2, ct = t16 & 3;
    int cg = ct ^ ((rt >> 1) & 3);
    gload_lds16(gbase + (size_t)rt * KK + cg * 8, dst + t16 * 8);
  }
}
template <int KK>
__device__ __forceinline__ void stage_tileB(const u16* __restrict__ gbase, u16* dst, int tid) {
  int t16 = tid;
  int rt = t16 >> 2, ct = t16 & 3;
  int cg = ct ^ ((rt >> 1) & 3);
  gload_lds16(gbase + (size_t)rt * KK + cg * 8, dst + t16 * 8);
}

// read 8 bf16 (16B) at [row][chunk*8] of a [*][32]-elem LDS tile, chunk 0..3 swizzled
__device__ __forceinline__ bf16x8 frag32(const u16* buf, int row, int chunk) {
  int ch = chunk ^ ((row >> 1) & 3);
  return *(const bf16x8*)&buf[row * 32 + ch * 8];
}

template <int NN, int KK, int COLG>
__global__ __launch_bounds__(512, 4) void gemm_qkv(
    const u16* __restrict__ A, const u16* __restrict__ Bm,
    const float* __restrict__ bias,
    u16* __restrict__ Qb, u16* __restrict__ Kb, u16* __restrict__ Vb) {
  __shared__ u16 As[2][8192];
  __shared__ u16 Bs[2][4096];
  const int tid = threadIdx.x;
  const int wave = tid >> 6;
  const int lane = tid & 63;
  const int l31 = lane & 31;
  const int hi = lane >> 5;
  const int wr = wave >> 1;
  const int wc = wave & 1;
  const int bid = blockIdx.x;
  const int xcd = bid & 7;
  const int local = bid >> 3;
  const int rlr = local / COLG;
  const int rlc = local - rlr * COLG;
  const int m0 = ((xcd >> 2) * 8 + rlr) * 256;
  const int n0 = ((xcd & 3) * COLG + rlc) * 128;
  const int NT = KK / 32;

  f32x16 acc[2][2];
#pragma unroll
  for (int i = 0; i < 2; ++i)
#pragma unroll
    for (int j = 0; j < 2; ++j)
#pragma unroll
      for (int r = 0; r < 16; ++r) acc[i][j][r] = 0.f;

  const u16* Ab = A + (size_t)m0 * KK;
  const u16* Bw = Bm + (size_t)n0 * KK;

  stage_tileA<KK>(Ab, &As[0][0], tid);
  stage_tileB<KK>(Bw, &Bs[0][0], tid);
  asm volatile("s_waitcnt vmcnt(0)");
  __syncthreads();

  int cur = 0;
  for (int t = 0; t < NT; ++t) {
    if (t + 1 < NT) {
      stage_tileA<KK>(Ab + (t + 1) * 32, &As[cur ^ 1][0], tid);
      stage_tileB<KK>(Bw + (t + 1) * 32, &Bs[cur ^ 1][0], tid);
      asm volatile("s_waitcnt vmcnt(3)");
    } else {
      asm volatile("s_waitcnt vmcnt(0)");
    }
    __builtin_amdgcn_s_barrier();
    __builtin_amdgcn_sched_barrier(0);

    bf16x8 af[2][2], bf[2][2];   // [mi2|ni2][kk]
#pragma unroll
    for (int mi2 = 0; mi2 < 2; ++mi2)
#pragma unroll
      for (int kk = 0; kk < 2; ++kk)
        af[mi2][kk] = frag32(&As[cur][0], wr * 64 + mi2 * 32 + l31, kk * 2 + hi);
#pragma unroll
    for (int ni2 = 0; ni2 < 2; ++ni2)
#pragma unroll
      for (int kk = 0; kk < 2; ++kk)
        bf[ni2][kk] = frag32(&Bs[cur][0], wc * 64 + ni2 * 32 + l31, kk * 2 + hi);
    asm volatile("s_waitcnt lgkmcnt(0)");
    __builtin_amdgcn_sched_barrier(0);
    __builtin_amdgcn_s_setprio(1);
#pragma unroll
    for (int mi2 = 0; mi2 < 2; ++mi2)
#pragma unroll
      for (int ni2 = 0; ni2 < 2; ++ni2)
#pragma unroll
        for (int kk = 0; kk < 2; ++kk)
          acc[mi2][ni2] = __builtin_amdgcn_mfma_f32_32x32x16_bf16(af[mi2][kk], bf[ni2][kk], acc[mi2][ni2], 0, 0, 0);
    __builtin_amdgcn_s_setprio(0);
    __builtin_amdgcn_s_barrier();
    cur ^= 1;
  }

  // epilogue: bias + Q/K/V scatter; n is per-lane constant within each ni2
#pragma unroll
  for (int ni2 = 0; ni2 < 2; ++ni2) {
    int n = n0 + wc * 64 + ni2 * 32 + l31;
    float bv = bias[n];
#pragma unroll
    for (int mi2 = 0; mi2 < 2; ++mi2) {
#pragma unroll
      for (int r = 0; r < 16; ++r) {
        int m = m0 + wr * 64 + mi2 * 32 + (r & 3) + 8 * (r >> 2) + 4 * hi;
        int bb = m >> 11;
        int ss = m & 2047;
        u16 hv = f2b(acc[mi2][ni2][r] + bv);
        if (n < 4096) {
          Qb[(((size_t)bb * NHh + (n >> 7)) * Ss + ss) * HDd + (n & 127)] = hv;
        } else if (n < 4352) {
          int idx2 = n - 4096;
          Kb[(((size_t)bb * KVHh + (idx2 >> 7)) * Ss + ss) * HDd + (idx2 & 127)] = hv;
        } else {
          int idx2 = n - 4352;
          Vb[(((size_t)bb * KVHh + (idx2 >> 7)) * Ss + ss) * HDd + (idx2 & 127)] = hv;
        }
      }
    }
  }
}

// ---------------- dense GEMM: 256x256 tile, 4-quadrant schedule (R15 form) ----------
// 16x16x32 MFMA — the 32x32 variant regressed here (R17 A/B): the deep-pipelined
// phases put LDS-reads on the critical path (T2 regime), and the 16x16 read pattern
// is the conflict-free one. Staging: A(kt+1) dbuf in P0/P1, B(kt+2) two-ahead in
// P2/P3 (B reads complete in P0), boundary vmcnt(4).
__global__ __launch_bounds__(512, 2) void gemm_d256(
    const u16* __restrict__ A, const u16* __restrict__ Bm,
    float* __restrict__ Cout) {
  __shared__ u16 SM[2][4][8192];    // [buf][Bh0,Bh1,Ah0,Ah1][128x64 bf16]
  const int tid = threadIdx.x;
  const int wave = tid >> 6;
  const int lane = tid & 63;
  const int lr = lane & 15;
  const int lk = lane >> 4;
  const int wr = wave >> 2;          // 0..1 (M half)
  const int wc = wave & 3;           // 0..3 (N quarter)
  const int bid = blockIdx.x;
  const int xcd = bid & 7;
  const int local = bid >> 3;
  const int m0 = ((xcd >> 2) * 8 + (local >> 2)) * 256;
  const int n0 = ((xcd & 3) * 4 + (local & 3)) * 256;
  const int NT = 64;

  f32x4 acc[8][4];
#pragma unroll
  for (int i = 0; i < 8; ++i)
#pragma unroll
    for (int j = 0; j < 4; ++j) acc[i][j] = (f32x4){0.f, 0.f, 0.f, 0.f};

  auto stage_half = [&](const u16* grows, int j, u16* dst) {
    if (j >= NT) return;
#pragma unroll
    for (int li = 0; li < 2; ++li) {
      int t16 = li * 512 + tid;
      int row = t16 >> 3, c = t16 & 7;
      int cs = c ^ (row & 7);
      gload_lds16(grows + (size_t)row * 4096 + j * 64 + cs * 8, dst + t16 * 8);
    }
  };
  const u16* Ah0g = A + (size_t)m0 * 4096;
  const u16* Ah1g = A + (size_t)(m0 + 128) * 4096;
  const u16* Bh0g = Bm + (size_t)n0 * 4096;
  const u16* Bh1g = Bm + (size_t)(n0 + 128) * 4096;

  stage_half(Ah0g, 0, &SM[0][2][0]);
  stage_half(Ah1g, 0, &SM[0][3][0]);
  stage_half(Bh0g, 0, &SM[0][0][0]);
  stage_half(Bh1g, 0, &SM[0][1][0]);
  stage_half(Bh0g, 1, &SM[1][0][0]);
  stage_half(Bh1g, 1, &SM[1][1][0]);
  asm volatile("s_waitcnt vmcnt(0)");
  __builtin_amdgcn_s_barrier();
  __builtin_amdgcn_sched_barrier(0);

  for (int kt = 0; kt < NT; ++kt) {
    const int cur = kt & 1;
    const int nxt = cur ^ 1;
    const u16* Ahl = &SM[cur][2 + wr][0];
    const u16* Bhl = &SM[cur][wc >> 1][0];
    const int rB0 = (wc & 1) * 64;
    auto rdA = [&](int r, int kk) {
      int ch = (kk * 4 + lk) ^ (r & 7);
      return *(const bf16x8*)&Ahl[r * 64 + ch * 8];
    };
    auto rdB = [&](int r, int kk) {
      int ch = (kk * 4 + lk) ^ (r & 7);
      return *(const bf16x8*)&Bhl[r * 64 + ch * 8];
    };

    bf16x8 bfr[4][2], af[2][2];
    // ---- P0: read B all (8) + A mi01 (4); stage A(kt+1) h0 -> SM[nxt][2] ----
#pragma unroll
    for (int ni = 0; ni < 4; ++ni)
#pragma unroll
      for (int kk = 0; kk < 2; ++kk)
        bfr[ni][kk] = rdB(rB0 + ni * 16 + lr, kk);
#pragma unroll
    for (int i = 0; i < 2; ++i)
#pragma unroll
      for (int kk = 0; kk < 2; ++kk)
        af[i][kk] = rdA(i * 16 + lr, kk);
    stage_half(Ah0g, kt + 1, &SM[nxt][2][0]);
    __builtin_amdgcn_s_barrier();
    asm volatile("s_waitcnt lgkmcnt(0)");
    __builtin_amdgcn_sched_barrier(0);
    __builtin_amdgcn_s_setprio(1);
#pragma unroll
    for (int i = 0; i < 2; ++i)
#pragma unroll
      for (int ni = 0; ni < 4; ++ni)
#pragma unroll
        for (int kk = 0; kk < 2; ++kk)
          acc[i][ni] = __builtin_amdgcn_mfma_f32_16x16x32_bf16(af[i][kk], bfr[ni][kk], acc[i][ni], 0, 0, 0);
    __builtin_amdgcn_s_setprio(0);
    __builtin_amdgcn_s_barrier();

    // ---- P1: read A mi23; stage A(kt+1) h1 -> SM[nxt][3] ----
#pragma unroll
    for (int i = 0; i < 2; ++i)
#pragma unroll
      for (int kk = 0; kk < 2; ++kk)
        af[i][kk] = rdA((2 + i) * 16 + lr, kk);
    stage_half(Ah1g, kt + 1, &SM[nxt][3][0]);
    __builtin_amdgcn_s_barrier();
    asm volatile("s_waitcnt lgkmcnt(0)");
    __builtin_amdgcn_sched_barrier(0);
    __builtin_amdgcn_s_setprio(1);
#pragma unroll
    for (int i = 0; i < 2; ++i)
#pragma unroll
      for (int ni = 0; ni < 4; ++ni)
#pragma unroll
        for (int kk = 0; kk < 2; ++kk)
          acc[2 + i][ni] = __builtin_amdgcn_mfma_f32_16x16x32_bf16(af[i][kk], bfr[ni][kk], acc[2 + i][ni], 0, 0, 0);
    __builtin_amdgcn_s_setprio(0);
    __builtin_amdgcn_s_barrier();

    // ---- P2: read A mi45; stage B(kt+2) h0 -> SM[cur][0] (B reads done in P0) ----
#pragma unroll
    for (int i = 0; i < 2; ++i)
#pragma unroll
      for (int kk = 0; kk < 2; ++kk)
        af[i][kk] = rdA((4 + i) * 16 + lr, kk);
    stage_half(Bh0g, kt + 2, &SM[cur][0][0]);
    __builtin_amdgcn_s_barrier();
    asm volatile("s_waitcnt lgkmcnt(0)");
    __builtin_amdgcn_sched_barrier(0);
    __builtin_amdgcn_s_setprio(1);
#pragma unroll
    for (int i = 0; i < 2; ++i)
#pragma unroll
      for (int ni = 0; ni < 4; ++ni)
#pragma unroll
        for (int kk = 0; kk < 2; ++kk)
          acc[4 + i][ni] = __builtin_amdgcn_mfma_f32_16x16x32_bf16(af[i][kk], bfr[ni][kk], acc[4 + i][ni], 0, 0, 0);
    __builtin_amdgcn_s_setprio(0);
    __builtin_amdgcn_s_barrier();

    // ---- P3: read A mi67; stage B(kt+2) h1 -> SM[cur][1]; boundary vmcnt ----
#pragma unroll
    for (int i = 0; i < 2; ++i)
#pragma unroll
      for (int kk = 0; kk < 2; ++kk)
        af[i][kk] = rdA((6 + i) * 16 + lr, kk);
    stage_half(Bh1g, kt + 2, &SM[cur][1][0]);
    __builtin_amdgcn_s_barrier();
    asm volatile("s_waitcnt lgkmcnt(0)");
    __builtin_amdgcn_sched_barrier(0);
    __builtin_amdgcn_s_setprio(1);
#pragma unroll
    for (int i = 0; i < 2; ++i)
#pragma unroll
      for (int ni = 0; ni < 4; ++ni)
#pragma unroll
        for (int kk = 0; kk < 2; ++kk)
          acc[6 + i][ni] = __builtin_amdgcn_mfma_f32_16x16x32_bf16(af[i][kk], bfr[ni][kk], acc[6 + i][ni], 0, 0, 0);
    __builtin_amdgcn_s_setprio(0);
    if (kt < NT - 2) {
      asm volatile("s_waitcnt vmcnt(4)");
    } else {
      asm volatile("s_waitcnt vmcnt(0)");
    }
    __builtin_amdgcn_s_barrier();
    __builtin_amdgcn_sched_barrier(0);
  }

  // epilogue: plain f32 store
#pragma unroll
  for (int mi = 0; mi < 8; ++mi)
#pragma unroll
    for (int ni = 0; ni < 4; ++ni) {
      int col = n0 + wc * 64 + ni * 16 + lr;
      int rowb = m0 + wr * 128 + mi * 16 + lk * 4;
#pragma unroll
      for (int j = 0; j < 4; ++j)
        Cout[(size_t)(rowb + j) * 4096 + col] = acc[mi][ni][j];
    }
}

// ---------------- causal GQA flash attention, 8-wave 32x32 swapped-QK^T ----------------
__global__ __launch_bounds__(512, 2) void attn_k(
    const u16* __restrict__ Qb, const u16* __restrict__ Kb,
    const u16* __restrict__ Vb, const float* __restrict__ rope,
    u16* __restrict__ Ctx) {
  __shared__ u16 Kt[2][64 * 128];
  __shared__ u16 Vt[2][128 * 64];
  const int tid = threadIdx.x;
  const int w = tid >> 6;
  const int lane = tid & 63;
  const int l31 = lane & 31;
  const int hi = lane >> 5;
  const int h = blockIdx.y, b = blockIdx.z;
  const int hkv = h >> 4;
  const u16* Qp = Qb + ((size_t)(b * NHh + h)) * Ss * HDd;
  const u16* Kp = Kb + ((size_t)(b * KVHh + hkv)) * Ss * HDd;
  const u16* Vp = Vb + ((size_t)(b * KVHh + hkv)) * Ss * HDd;

  const float scale = 0.08838834764831845f;
  const float L2E = 1.4426950408889634f;

  for (int hp = 0; hp < 2; ++hp) {
    const int qt = hp == 0 ? (7 - (int)blockIdx.x) : (int)blockIdx.x;
    const int qs = qt * 256;
    const int qw = qs + w * 32;
    const int qrow = qw + l31;
    const int nt = qs / 64 + 4;

    bf16x8 qf[8];
#pragma unroll
    for (int ds = 0; ds < 8; ++ds)
      qf[ds] = *(const bf16x8*)&Qp[(size_t)qrow * HDd + ds * 16 + hi * 8];
#pragma unroll
    for (int ds = 0; ds < 4; ++ds) {
      bf16x8 q = qf[ds];
      bf16x8 o;
#pragma unroll
      for (int i = 0; i < 4; ++i) {
        int p = ds * 8 + hi * 4 + i;
        float2 rc = *(const float2*)&rope[(((size_t)b * Ss + qrow) * 32 + p) * 2];
        float x0 = b2f((u16)q[2 * i]), x1 = b2f((u16)q[2 * i + 1]);
        o[2 * i] = (short)f2b(x0 * rc.x - x1 * rc.y);
        o[2 * i + 1] = (short)f2b(x1 * rc.x + x0 * rc.y);
      }
      qf[ds] = o;
    }

    f32x16 accO[4];
#pragma unroll
    for (int i = 0; i < 4; ++i)
#pragma unroll
      for (int r = 0; r < 16; ++r) accO[i][r] = 0.f;
    float m_r = -3.0e38f, l_r = 0.f;

    {
#pragma unroll
      for (int i = 0; i < 2; ++i) {
        int slot = w * 2 + i;
        int r = slot * 4 + (lane >> 4);
        int p = lane & 15;
        int gc = (p & 8) | ((p ^ r) & 7);
        gload_lds16(Kp + (size_t)r * HDd + gc * 8, &Kt[0][slot * 512]);
      }
      bf16x8 v0 = *(const bf16x8*)&Vp[(size_t)lane * HDd + w * 16];
      bf16x8 v1 = *(const bf16x8*)&Vp[(size_t)lane * HDd + w * 16 + 8];
      u32x4 sv = __builtin_bit_cast(u32x4, (lane & 1) ? v0 : v1);
      u32x4 rv;
      rv.x = __shfl_xor(sv.x, 1); rv.y = __shfl_xor(sv.y, 1);
      rv.z = __shfl_xor(sv.z, 1); rv.w = __shfl_xor(sv.w, 1);
      bf16x8 recv = __builtin_bit_cast(bf16x8, rv);
      int kvp = lane >> 1;
#pragma unroll
      for (int i = 0; i < 8; ++i) {
        int d = w * 16 + (lane & 1) * 8 + i;
        u16 lo = (lane & 1) ? (u16)recv[i] : (u16)v0[i];
        u16 hb = (lane & 1) ? (u16)v1[i] : (u16)recv[i];
        u32 val = (u32)lo | ((u32)hb << 16);
        int cp = (kvp >> 2) ^ (d & 7);
        *(u32*)&Vt[0][d * 64 + cp * 8 + (kvp & 3) * 2] = val;
      }
    }
    __syncthreads();

    for (int t = 0; t < nt; ++t) {
      const int j0 = t * 64;
      const int cur = t & 1;
      const bool havenext = (t + 1 < nt);
      bf16x8 nv0, nv1;
      if (havenext) {
        const int j1 = j0 + 64;
#pragma unroll
        for (int i = 0; i < 2; ++i) {
          int slot = w * 2 + i;
          int r = slot * 4 + (lane >> 4);
          int p = lane & 15;
          int gc = (p & 8) | ((p ^ r) & 7);
          gload_lds16(Kp + (size_t)(j1 + r) * HDd + gc * 8, &Kt[cur ^ 1][slot * 512]);
        }
        nv0 = *(const bf16x8*)&Vp[(size_t)(j1 + lane) * HDd + w * 16];
        nv1 = *(const bf16x8*)&Vp[(size_t)(j1 + lane) * HDd + w * 16 + 8];
      }

      if (j0 <= qw + 31) {
        f32x16 aS[2];
#pragma unroll
        for (int a = 0; a < 2; ++a)
#pragma unroll
          for (int r = 0; r < 16; ++r) aS[a][r] = 0.f;
#pragma unroll
        for (int kvb = 0; kvb < 2; ++kvb) {
          int r = kvb * 32 + l31;
#pragma unroll
          for (int ds = 0; ds < 8; ++ds) {
            int c = ds * 2 + hi;
            int cp = (c & 8) | ((c ^ r) & 7);
            bf16x8 kf = *(const bf16x8*)&Kt[cur][r * 128 + cp * 8];
            aS[kvb] = __builtin_amdgcn_mfma_f32_32x32x16_bf16(kf, qf[ds], aS[kvb], 0, 0, 0);
          }
        }
        const bool needmask = (j0 + 63 > qw);
        float mx = -3.0e38f;
#pragma unroll
        for (int a = 0; a < 2; ++a)
#pragma unroll
          for (int r = 0; r < 16; ++r) {
            float s = aS[a][r] * scale;
            if (needmask) {
              int kv = j0 + a * 32 + (r & 3) + 8 * (r >> 2) + 4 * hi;
              s = (kv > qrow) ? -3.0e38f : s;
            }
            aS[a][r] = s;
            mx = fmaxf(mx, s);
          }
        mx = fmaxf(mx, __shfl_xor(mx, 32));
        if (!__all(mx - m_r <= 8.0f)) {
          float mnew = fmaxf(m_r, mx);
          float corr = __builtin_amdgcn_exp2f((m_r - mnew) * L2E);
          l_r *= corr;
#pragma unroll
          for (int i = 0; i < 4; ++i)
#pragma unroll
            for (int r = 0; r < 16; ++r) accO[i][r] *= corr;
          m_r = mnew;
        }
        float sum = 0.f;
#pragma unroll
        for (int a = 0; a < 2; ++a)
#pragma unroll
          for (int r = 0; r < 16; ++r) {
            float pe = __builtin_amdgcn_exp2f((aS[a][r] - m_r) * L2E);
            aS[a][r] = pe;
            sum += pe;
          }
        sum += __shfl_xor(sum, 32);
        l_r += sum;

        u32 cc0[2][4], cc1[2][4];
#pragma unroll
        for (int a = 0; a < 2; ++a)
#pragma unroll
          for (int g = 0; g < 4; ++g) {
            cc0[a][g] = cvtpk(aS[a][g * 4 + 0], aS[a][g * 4 + 1]);
            cc1[a][g] = cvtpk(aS[a][g * 4 + 2], aS[a][g * 4 + 3]);
          }
        bf16x8 pa[4];
#pragma unroll
        for (int ks = 0; ks < 4; ++ks) {
          int a = ks >> 1, g0 = (ks & 1) * 2;
          u32 w0 = cc0[a][g0], w2 = cc0[a][g0 + 1];
          u32 w1 = cc1[a][g0], w3 = cc1[a][g0 + 1];
          plswap(w0, w2);
          plswap(w1, w3);
          u32x4 tv; tv.x = w0; tv.y = w1; tv.z = w2; tv.w = w3;
          pa[ks] = __builtin_bit_cast(bf16x8, tv);
        }
#pragma unroll
        for (int dblk = 0; dblk < 4; ++dblk) {
          int d = dblk * 32 + l31;
#pragma unroll
          for (int ks = 0; ks < 4; ++ks) {
            int c = ks * 2 + hi;
            int cp = c ^ (d & 7);
            bf16x8 vf = *(const bf16x8*)&Vt[cur][d * 64 + cp * 8];
            accO[dblk] = __builtin_amdgcn_mfma_f32_32x32x16_bf16(vf, pa[ks], accO[dblk], 0, 0, 0);
          }
        }
      }

      if (havenext) {
        u32x4 sv = __builtin_bit_cast(u32x4, (lane & 1) ? nv0 : nv1);
        u32x4 rv;
        rv.x = __shfl_xor(sv.x, 1); rv.y = __shfl_xor(sv.y, 1);
        rv.z = __shfl_xor(sv.z, 1); rv.w = __shfl_xor(sv.w, 1);
        bf16x8 recv = __builtin_bit_cast(bf16x8, rv);
        int kvp = lane >> 1;
#pragma unroll
        for (int i = 0; i < 8; ++i) {
          int d = w * 16 + (lane & 1) * 8 + i;
          u16 lo = (lane & 1) ? (u16)recv[i] : (u16)nv0[i];
          u16 hb = (lane & 1) ? (u16)nv1[i] : (u16)recv[i];
          u32 val = (u32)lo | ((u32)hb << 16);
          int cp = (kvp >> 2) ^ (d & 7);
          *(u32*)&Vt[cur ^ 1][d * 64 + cp * 8 + (kvp & 3) * 2] = val;
        }
      }
      __syncthreads();
    }

    {
      float il = 1.0f / l_r;
      size_t rb = ((size_t)b * Ss + qrow) * (size_t)(NHh * HDd) + (size_t)h * HDd;
#pragma unroll
      for (int dblk = 0; dblk < 4; ++dblk)
#pragma unroll
        for (int g = 0; g < 4; ++g) {
          int d0 = dblk * 32 + g * 8 + hi * 4;
          u64 pack = (u64)f2b(accO[dblk][g * 4 + 0] * il) |
                     ((u64)f2b(accO[dblk][g * 4 + 1] * il) << 16) |
                     ((u64)f2b(accO[dblk][g * 4 + 2] * il) << 32) |
                     ((u64)f2b(accO[dblk][g * 4 + 3] * il) << 48);
          *(u64*)&Ctx[rb + d0] = pack;
        }
    }
    __syncthreads();
  }
}

extern "C" void kernel_launch(void* const* d_in, const int* in_sizes, int n_in,
                              void* d_out, int out_size, void* d_ws, size_t ws_size,
                              hipStream_t stream) {
  const float* hidden = (const float*)d_in[0];
  const float* rope = (const float*)d_in[1];
  const float* Wqkv = (const float*)d_in[3];
  const float* bqkv = (const float*)d_in[4];
  const float* Wdense = (const float*)d_in[5];
  float* out = (float*)d_out;

  // ws layout: 104 MB total (L3-friendly).
  char* w = (char*)d_ws;
  u16* Xbf = (u16*)w;
  u16* ctx = Xbf;
  w += (size_t)33554432;
  u16* Wq = (u16*)w;
  u16* Wd = Wq;                        // alias: written AFTER QKV GEMM consumed Wq
  w += (size_t)37748736;
  u16* Qb = (u16*)w; w += (size_t)33554432;
  u16* Kb = (u16*)w; w += (size_t)2097152;
  u16* Vb = (u16*)w; w += (size_t)2097152;

  // 1. fused convert: hidden->Xbf, Wqkv->Wq
  cvt2_k<<<34816, 256, 0, stream>>>(hidden, Xbf, Wqkv, Wq);
  // 2. QKV GEMM (32x32x16): 576 blocks; regions 8x9 per XCD
  gemm_qkv<4608, 4096, 9><<<dim3(576), 512, 0, stream>>>(
      Xbf, Wq, bqkv, Qb, Kb, Vb);
  // 3. RoPE on K only (Q's rope fused into attn_k)
  rope_k<<<(Bb * KVHh * Ss * 32 + 255) / 256, 256, 0, stream>>>(Kb, rope, KVHh);
  // 4. convert Wdense into Wq's region
  cvtW_k<<<16384, 256, 0, stream>>>(Wdense, Wd);
  // 5. flash attention (balanced causal pairing, fused Q-RoPE)
  attn_k<<<dim3(4, NHh, Bb), 512, 0, stream>>>(Qb, Kb, Vb, rope, ctx);
  // 6. dense GEMM: 256^2 4-quadrant schedule, 16x16x32 MFMA (R15 form); 256 blocks
  gemm_d256<<<dim3(256), 512, 0, stream>>>(ctx, Wd, out);
}

// Round 19
// 471.122 us; speedup vs baseline: 1.0686x; 1.0353x over previous
//
#include <hip/hip_runtime.h>
#include <hip/hip_bf16.h>
#include <stdint.h>

#define Bb 2
#define Ss 2048
#define Hh 4096
#define NHh 32
#define HDd 128
#define KVHh 2

typedef __attribute__((ext_vector_type(8))) short bf16x8;
typedef __attribute__((ext_vector_type(4))) float f32x4;
typedef __attribute__((ext_vector_type(16))) float f32x16;
typedef __attribute__((ext_vector_type(4))) unsigned int u32x4;
typedef unsigned short u16;
typedef unsigned int u32;
typedef unsigned long long u64;

__device__ __forceinline__ u16 f2b(float f) {
  union { float f; u32 u; } v; v.f = f;
  u32 r = v.u + 0x7fffu + ((v.u >> 16) & 1u);
  return (u16)(r >> 16);
}
__device__ __forceinline__ float b2f(u16 h) {
  union { u32 u; float f; } v; v.u = ((u32)h) << 16;
  return v.f;
}

__device__ __forceinline__ u32 cvtpk(float lo, float hi_) {
  u32 r;
  asm("v_cvt_pk_bf16_f32 %0, %1, %2" : "=v"(r) : "v"(lo), "v"(hi_));
  return r;
}
__device__ __forceinline__ void plswap(u32& x, u32& y) {
  asm volatile("v_permlane32_swap_b32 %0, %1" : "+v"(x), "+v"(y));
}

// async global->LDS, 16B per lane; LDS dest is wave-uniform base + lane*16
__device__ __forceinline__ void gload_lds16(const u16* g, u16* l) {
  __builtin_amdgcn_global_load_lds(
      (const __attribute__((address_space(1))) u32*)(uintptr_t)g,
      (__attribute__((address_space(3))) u32*)(u32)(uintptr_t)l,
      16, 0, 0);
}

// ---------------- fused f32 -> bf16 convert: hidden + Wqkv ----------------
__global__ void cvt2_k(const float* __restrict__ a, u16* __restrict__ oa,
                       const float* __restrict__ b, u16* __restrict__ ob) {
  int i = blockIdx.x * blockDim.x + threadIdx.x;
  const float* src;
  u16* dst;
  int off;
  if (i < 4194304) { src = a; dst = oa; off = i; }
  else { src = b; dst = ob; off = i - 4194304; }
  int idx = off * 4;
  float4 v = *(const float4*)&src[idx];
  u64 pack = (u64)f2b(v.x) | ((u64)f2b(v.y) << 16) |
             ((u64)f2b(v.z) << 32) | ((u64)f2b(v.w) << 48);
  *(u64*)&dst[idx] = pack;
}

// ---------------- f32 -> bf16 convert (Wdense, after QKV GEMM) ----------
__global__ void cvtW_k(const float* __restrict__ in, u16* __restrict__ out) {
  int i = blockIdx.x * blockDim.x + threadIdx.x;
  int idx = i * 4;
  float4 v = *(const float4*)&in[idx];
  u64 pack = (u64)f2b(v.x) | ((u64)f2b(v.y) << 16) |
             ((u64)f2b(v.z) << 32) | ((u64)f2b(v.w) << 48);
  *(u64*)&out[idx] = pack;
}

// ---------------- RoPE in-place on (B, nheads, S, HD) bf16 — K only ----------------
__global__ void rope_k(u16* __restrict__ X, const float* __restrict__ rope, int nheads) {
  int i = blockIdx.x * blockDim.x + threadIdx.x;
  int p = i & 31;
  int s = (i >> 5) & (Ss - 1);
  int bh = i >> 16;
  if (bh >= Bb * nheads) return;
  int b = bh / nheads;
  size_t base = ((size_t)bh * Ss + s) * HDd + p * 2;
  u32 x01 = *(u32*)&X[base];
  float x0 = b2f((u16)(x01 & 0xffff));
  float x1 = b2f((u16)(x01 >> 16));
  float2 rc = *(const float2*)&rope[(((size_t)b * Ss + s) * 32 + p) * 2];
  float o0 = x0 * rc.x - x1 * rc.y;
  float o1 = x1 * rc.x + x0 * rc.y;
  u32 o = (u32)f2b(o0) | ((u32)f2b(o1) << 16);
  *(u32*)&X[base] = o;
}

// ---------------- QKV GEMM: 256x128 tile, BK=32, counted-vmcnt dbuf (R8/R15 form) ----
// 16x16x32 MFMA. R18 A/B algebra: the 32x32 variant was net-negative in graph
// replay (+16 us) despite better per-dispatch rocprof — reverted (rule #13).
template <int KK>
__device__ __forceinline__ void stage_tileA(const u16* __restrict__ gbase, u16* dst, int tid) {
#pragma unroll
  for (int li = 0; li < 2; ++li) {
    int t16 = li * 512 + tid;
    int rt = t16 >> 2, ct = t16 & 3;
    int cg = ct ^ ((rt >> 1) & 3);
    gload_lds16(gbase + (size_t)rt * KK + cg * 8, dst + t16 * 8);
  }
}
template <int KK>
__device__ __forceinline__ void stage_tileB(const u16* __restrict__ gbase, u16* dst, int tid) {
  int t16 = tid;
  int rt = t16 >> 2, ct = t16 & 3;
  int cg = ct ^ ((rt >> 1) & 3);
  gload_lds16(gbase + (size_t)rt * KK + cg * 8, dst + t16 * 8);
}

__device__ __forceinline__ bf16x8 frag128(const u16* buf, int row, int lk) {
  int ch = lk ^ ((row >> 1) & 3);
  return *(const bf16x8*)&buf[row * 32 + ch * 8];
}

template <int NN, int KK, int COLG>
__global__ __launch_bounds__(512, 4) void gemm_qkv(
    const u16* __restrict__ A, const u16* __restrict__ Bm,
    const float* __restrict__ bias,
    u16* __restrict__ Qb, u16* __restrict__ Kb, u16* __restrict__ Vb) {
  __shared__ u16 As[2][8192];
  __shared__ u16 Bs[2][4096];
  const int tid = threadIdx.x;
  const int wave = tid >> 6;
  const int lane = tid & 63;
  const int lr = lane & 15;
  const int lk = lane >> 4;
  const int wr = wave >> 1;
  const int wc = wave & 1;
  const int bid = blockIdx.x;
  const int xcd = bid & 7;
  const int local = bid >> 3;
  const int rlr = local / COLG;
  const int rlc = local - rlr * COLG;
  const int m0 = ((xcd >> 2) * 8 + rlr) * 256;
  const int n0 = ((xcd & 3) * COLG + rlc) * 128;
  const int NT = KK / 32;

  f32x4 acc[4][4];
#pragma unroll
  for (int i = 0; i < 4; ++i)
#pragma unroll
    for (int j = 0; j < 4; ++j) acc[i][j] = (f32x4){0.f, 0.f, 0.f, 0.f};

  const u16* Ab = A + (size_t)m0 * KK;
  const u16* Bw = Bm + (size_t)n0 * KK;

  stage_tileA<KK>(Ab, &As[0][0], tid);
  stage_tileB<KK>(Bw, &Bs[0][0], tid);
  asm volatile("s_waitcnt vmcnt(0)");
  __syncthreads();

  int cur = 0;
  for (int t = 0; t < NT; ++t) {
    if (t + 1 < NT) {
      stage_tileA<KK>(Ab + (t + 1) * 32, &As[cur ^ 1][0], tid);
      stage_tileB<KK>(Bw + (t + 1) * 32, &Bs[cur ^ 1][0], tid);
      asm volatile("s_waitcnt vmcnt(3)");
    } else {
      asm volatile("s_waitcnt vmcnt(0)");
    }
    __builtin_amdgcn_s_barrier();
    __builtin_amdgcn_sched_barrier(0);

    bf16x8 af[4], bf[4];
#pragma unroll
    for (int mi = 0; mi < 4; ++mi)
      af[mi] = frag128(&As[cur][0], wr * 64 + mi * 16 + lr, lk);
#pragma unroll
    for (int ni = 0; ni < 4; ++ni)
      bf[ni] = frag128(&Bs[cur][0], wc * 64 + ni * 16 + lr, lk);
    asm volatile("s_waitcnt lgkmcnt(0)");
    __builtin_amdgcn_sched_barrier(0);
    __builtin_amdgcn_s_setprio(1);
#pragma unroll
    for (int mi = 0; mi < 4; ++mi)
#pragma unroll
      for (int ni = 0; ni < 4; ++ni)
        acc[mi][ni] = __builtin_amdgcn_mfma_f32_16x16x32_bf16(af[mi], bf[ni], acc[mi][ni], 0, 0, 0);
    __builtin_amdgcn_s_setprio(0);
    __builtin_amdgcn_s_barrier();
    cur ^= 1;
  }

  // epilogue: bias + Q/K/V scatter
#pragma unroll
  for (int ni = 0; ni < 4; ++ni) {
    int n = n0 + wc * 64 + ni * 16 + lr;
    float bv = bias[n];
#pragma unroll
    for (int mi = 0; mi < 4; ++mi) {
      int mb = m0 + wr * 64 + mi * 16 + lk * 4;
#pragma unroll
      for (int j = 0; j < 4; ++j) {
        int m = mb + j;
        int bb = m >> 11;
        int ss = m & 2047;
        u16 hv = f2b(acc[mi][ni][j] + bv);
        if (n < 4096) {
          Qb[(((size_t)bb * NHh + (n >> 7)) * Ss + ss) * HDd + (n & 127)] = hv;
        } else if (n < 4352) {
          int idx2 = n - 4096;
          Kb[(((size_t)bb * KVHh + (idx2 >> 7)) * Ss + ss) * HDd + (idx2 & 127)] = hv;
        } else {
          int idx2 = n - 4352;
          Vb[(((size_t)bb * KVHh + (idx2 >> 7)) * Ss + ss) * HDd + (idx2 & 127)] = hv;
        }
      }
    }
  }
}

// ---------------- dense GEMM: 256x256 tile, 4-quadrant schedule (R15 form) ----------
// 16x16x32 MFMA. Staging: A(kt+1) dbuf in P0/P1 (opposite buffer), B(kt+2)
// two-ahead in P2/P3 (B reads complete in P0), boundary vmcnt(4). Grid 256 = 1/CU.
__global__ __launch_bounds__(512, 2) void gemm_d256(
    const u16* __restrict__ A, const u16* __restrict__ Bm,
    float* __restrict__ Cout) {
  __shared__ u16 SM[2][4][8192];    // [buf][Bh0,Bh1,Ah0,Ah1][128x64 bf16]
  const int tid = threadIdx.x;
  const int wave = tid >> 6;
  const int lane = tid & 63;
  const int lr = lane & 15;
  const int lk = lane >> 4;
  const int wr = wave >> 2;          // 0..1 (M half)
  const int wc = wave & 3;           // 0..3 (N quarter)
  const int bid = blockIdx.x;
  const int xcd = bid & 7;
  const int local = bid >> 3;
  const int m0 = ((xcd >> 2) * 8 + (local >> 2)) * 256;
  const int n0 = ((xcd & 3) * 4 + (local & 3)) * 256;
  const int NT = 64;

  f32x4 acc[8][4];
#pragma unroll
  for (int i = 0; i < 8; ++i)
#pragma unroll
    for (int j = 0; j < 4; ++j) acc[i][j] = (f32x4){0.f, 0.f, 0.f, 0.f};

  auto stage_half = [&](const u16* grows, int j, u16* dst) {
    if (j >= NT) return;
#pragma unroll
    for (int li = 0; li < 2; ++li) {
      int t16 = li * 512 + tid;
      int row = t16 >> 3, c = t16 & 7;
      int cs = c ^ (row & 7);
      gload_lds16(grows + (size_t)row * 4096 + j * 64 + cs * 8, dst + t16 * 8);
    }
  };
  const u16* Ah0g = A + (size_t)m0 * 4096;
  const u16* Ah1g = A + (size_t)(m0 + 128) * 4096;
  const u16* Bh0g = Bm + (size_t)n0 * 4096;
  const u16* Bh1g = Bm + (size_t)(n0 + 128) * 4096;

  stage_half(Ah0g, 0, &SM[0][2][0]);
  stage_half(Ah1g, 0, &SM[0][3][0]);
  stage_half(Bh0g, 0, &SM[0][0][0]);
  stage_half(Bh1g, 0, &SM[0][1][0]);
  stage_half(Bh0g, 1, &SM[1][0][0]);
  stage_half(Bh1g, 1, &SM[1][1][0]);
  asm volatile("s_waitcnt vmcnt(0)");
  __builtin_amdgcn_s_barrier();
  __builtin_amdgcn_sched_barrier(0);

  for (int kt = 0; kt < NT; ++kt) {
    const int cur = kt & 1;
    const int nxt = cur ^ 1;
    const u16* Ahl = &SM[cur][2 + wr][0];
    const u16* Bhl = &SM[cur][wc >> 1][0];
    const int rB0 = (wc & 1) * 64;
    auto rdA = [&](int r, int kk) {
      int ch = (kk * 4 + lk) ^ (r & 7);
      return *(const bf16x8*)&Ahl[r * 64 + ch * 8];
    };
    auto rdB = [&](int r, int kk) {
      int ch = (kk * 4 + lk) ^ (r & 7);
      return *(const bf16x8*)&Bhl[r * 64 + ch * 8];
    };

    bf16x8 bfr[4][2], af[2][2];
    // ---- P0: read B all (8) + A mi01 (4); stage A(kt+1) h0 -> SM[nxt][2] ----
#pragma unroll
    for (int ni = 0; ni < 4; ++ni)
#pragma unroll
      for (int kk = 0; kk < 2; ++kk)
        bfr[ni][kk] = rdB(rB0 + ni * 16 + lr, kk);
#pragma unroll
    for (int i = 0; i < 2; ++i)
#pragma unroll
      for (int kk = 0; kk < 2; ++kk)
        af[i][kk] = rdA(i * 16 + lr, kk);
    stage_half(Ah0g, kt + 1, &SM[nxt][2][0]);
    __builtin_amdgcn_s_barrier();
    asm volatile("s_waitcnt lgkmcnt(0)");
    __builtin_amdgcn_sched_barrier(0);
    __builtin_amdgcn_s_setprio(1);
#pragma unroll
    for (int i = 0; i < 2; ++i)
#pragma unroll
      for (int ni = 0; ni < 4; ++ni)
#pragma unroll
        for (int kk = 0; kk < 2; ++kk)
          acc[i][ni] = __builtin_amdgcn_mfma_f32_16x16x32_bf16(af[i][kk], bfr[ni][kk], acc[i][ni], 0, 0, 0);
    __builtin_amdgcn_s_setprio(0);
    __builtin_amdgcn_s_barrier();

    // ---- P1: read A mi23; stage A(kt+1) h1 -> SM[nxt][3] ----
#pragma unroll
    for (int i = 0; i < 2; ++i)
#pragma unroll
      for (int kk = 0; kk < 2; ++kk)
        af[i][kk] = rdA((2 + i) * 16 + lr, kk);
    stage_half(Ah1g, kt + 1, &SM[nxt][3][0]);
    __builtin_amdgcn_s_barrier();
    asm volatile("s_waitcnt lgkmcnt(0)");
    __builtin_amdgcn_sched_barrier(0);
    __builtin_amdgcn_s_setprio(1);
#pragma unroll
    for (int i = 0; i < 2; ++i)
#pragma unroll
      for (int ni = 0; ni < 4; ++ni)
#pragma unroll
        for (int kk = 0; kk < 2; ++kk)
          acc[2 + i][ni] = __builtin_amdgcn_mfma_f32_16x16x32_bf16(af[i][kk], bfr[ni][kk], acc[2 + i][ni], 0, 0, 0);
    __builtin_amdgcn_s_setprio(0);
    __builtin_amdgcn_s_barrier();

    // ---- P2: read A mi45; stage B(kt+2) h0 -> SM[cur][0] (B reads done in P0) ----
#pragma unroll
    for (int i = 0; i < 2; ++i)
#pragma unroll
      for (int kk = 0; kk < 2; ++kk)
        af[i][kk] = rdA((4 + i) * 16 + lr, kk);
    stage_half(Bh0g, kt + 2, &SM[cur][0][0]);
    __builtin_amdgcn_s_barrier();
    asm volatile("s_waitcnt lgkmcnt(0)");
    __builtin_amdgcn_sched_barrier(0);
    __builtin_amdgcn_s_setprio(1);
#pragma unroll
    for (int i = 0; i < 2; ++i)
#pragma unroll
      for (int ni = 0; ni < 4; ++ni)
#pragma unroll
        for (int kk = 0; kk < 2; ++kk)
          acc[4 + i][ni] = __builtin_amdgcn_mfma_f32_16x16x32_bf16(af[i][kk], bfr[ni][kk], acc[4 + i][ni], 0, 0, 0);
    __builtin_amdgcn_s_setprio(0);
    __builtin_amdgcn_s_barrier();

    // ---- P3: read A mi67; stage B(kt+2) h1 -> SM[cur][1]; boundary vmcnt ----
#pragma unroll
    for (int i = 0; i < 2; ++i)
#pragma unroll
      for (int kk = 0; kk < 2; ++kk)
        af[i][kk] = rdA((6 + i) * 16 + lr, kk);
    stage_half(Bh1g, kt + 2, &SM[cur][1][0]);
    __builtin_amdgcn_s_barrier();
    asm volatile("s_waitcnt lgkmcnt(0)");
    __builtin_amdgcn_sched_barrier(0);
    __builtin_amdgcn_s_setprio(1);
#pragma unroll
    for (int i = 0; i < 2; ++i)
#pragma unroll
      for (int ni = 0; ni < 4; ++ni)
#pragma unroll
        for (int kk = 0; kk < 2; ++kk)
          acc[6 + i][ni] = __builtin_amdgcn_mfma_f32_16x16x32_bf16(af[i][kk], bfr[ni][kk], acc[6 + i][ni], 0, 0, 0);
    __builtin_amdgcn_s_setprio(0);
    if (kt < NT - 2) {
      asm volatile("s_waitcnt vmcnt(4)");
    } else {
      asm volatile("s_waitcnt vmcnt(0)");
    }
    __builtin_amdgcn_s_barrier();
    __builtin_amdgcn_sched_barrier(0);
  }

  // epilogue: plain f32 store
#pragma unroll
  for (int mi = 0; mi < 8; ++mi)
#pragma unroll
    for (int ni = 0; ni < 4; ++ni) {
      int col = n0 + wc * 64 + ni * 16 + lr;
      int rowb = m0 + wr * 128 + mi * 16 + lk * 4;
#pragma unroll
      for (int j = 0; j < 4; ++j)
        Cout[(size_t)(rowb + j) * 4096 + col] = acc[mi][ni][j];
    }
}

// ---------------- causal GQA flash attention, 8-wave 32x32 swapped-QK^T ----------------
__global__ __launch_bounds__(512, 2) void attn_k(
    const u16* __restrict__ Qb, const u16* __restrict__ Kb,
    const u16* __restrict__ Vb, const float* __restrict__ rope,
    u16* __restrict__ Ctx) {
  __shared__ u16 Kt[2][64 * 128];
  __shared__ u16 Vt[2][128 * 64];
  const int tid = threadIdx.x;
  const int w = tid >> 6;
  const int lane = tid & 63;
  const int l31 = lane & 31;
  const int hi = lane >> 5;
  const int h = blockIdx.y, b = blockIdx.z;
  const int hkv = h >> 4;
  const u16* Qp = Qb + ((size_t)(b * NHh + h)) * Ss * HDd;
  const u16* Kp = Kb + ((size_t)(b * KVHh + hkv)) * Ss * HDd;
  const u16* Vp = Vb + ((size_t)(b * KVHh + hkv)) * Ss * HDd;

  const float scale = 0.08838834764831845f;
  const float L2E = 1.4426950408889634f;

  for (int hp = 0; hp < 2; ++hp) {
    const int qt = hp == 0 ? (7 - (int)blockIdx.x) : (int)blockIdx.x;
    const int qs = qt * 256;
    const int qw = qs + w * 32;
    const int qrow = qw + l31;
    const int nt = qs / 64 + 4;

    bf16x8 qf[8];
#pragma unroll
    for (int ds = 0; ds < 8; ++ds)
      qf[ds] = *(const bf16x8*)&Qp[(size_t)qrow * HDd + ds * 16 + hi * 8];
#pragma unroll
    for (int ds = 0; ds < 4; ++ds) {
      bf16x8 q = qf[ds];
      bf16x8 o;
#pragma unroll
      for (int i = 0; i < 4; ++i) {
        int p = ds * 8 + hi * 4 + i;
        float2 rc = *(const float2*)&rope[(((size_t)b * Ss + qrow) * 32 + p) * 2];
        float x0 = b2f((u16)q[2 * i]), x1 = b2f((u16)q[2 * i + 1]);
        o[2 * i] = (short)f2b(x0 * rc.x - x1 * rc.y);
        o[2 * i + 1] = (short)f2b(x1 * rc.x + x0 * rc.y);
      }
      qf[ds] = o;
    }

    f32x16 accO[4];
#pragma unroll
    for (int i = 0; i < 4; ++i)
#pragma unroll
      for (int r = 0; r < 16; ++r) accO[i][r] = 0.f;
    float m_r = -3.0e38f, l_r = 0.f;

    {
#pragma unroll
      for (int i = 0; i < 2; ++i) {
        int slot = w * 2 + i;
        int r = slot * 4 + (lane >> 4);
        int p = lane & 15;
        int gc = (p & 8) | ((p ^ r) & 7);
        gload_lds16(Kp + (size_t)r * HDd + gc * 8, &Kt[0][slot * 512]);
      }
      bf16x8 v0 = *(const bf16x8*)&Vp[(size_t)lane * HDd + w * 16];
      bf16x8 v1 = *(const bf16x8*)&Vp[(size_t)lane * HDd + w * 16 + 8];
      u32x4 sv = __builtin_bit_cast(u32x4, (lane & 1) ? v0 : v1);
      u32x4 rv;
      rv.x = __shfl_xor(sv.x, 1); rv.y = __shfl_xor(sv.y, 1);
      rv.z = __shfl_xor(sv.z, 1); rv.w = __shfl_xor(sv.w, 1);
      bf16x8 recv = __builtin_bit_cast(bf16x8, rv);
      int kvp = lane >> 1;
#pragma unroll
      for (int i = 0; i < 8; ++i) {
        int d = w * 16 + (lane & 1) * 8 + i;
        u16 lo = (lane & 1) ? (u16)recv[i] : (u16)v0[i];
        u16 hb = (lane & 1) ? (u16)v1[i] : (u16)recv[i];
        u32 val = (u32)lo | ((u32)hb << 16);
        int cp = (kvp >> 2) ^ (d & 7);
        *(u32*)&Vt[0][d * 64 + cp * 8 + (kvp & 3) * 2] = val;
      }
    }
    __syncthreads();

    for (int t = 0; t < nt; ++t) {
      const int j0 = t * 64;
      const int cur = t & 1;
      const bool havenext = (t + 1 < nt);
      bf16x8 nv0, nv1;
      if (havenext) {
        const int j1 = j0 + 64;
#pragma unroll
        for (int i = 0; i < 2; ++i) {
          int slot = w * 2 + i;
          int r = slot * 4 + (lane >> 4);
          int p = lane & 15;
          int gc = (p & 8) | ((p ^ r) & 7);
          gload_lds16(Kp + (size_t)(j1 + r) * HDd + gc * 8, &Kt[cur ^ 1][slot * 512]);
        }
        nv0 = *(const bf16x8*)&Vp[(size_t)(j1 + lane) * HDd + w * 16];
        nv1 = *(const bf16x8*)&Vp[(size_t)(j1 + lane) * HDd + w * 16 + 8];
      }

      if (j0 <= qw + 31) {
        f32x16 aS[2];
#pragma unroll
        for (int a = 0; a < 2; ++a)
#pragma unroll
          for (int r = 0; r < 16; ++r) aS[a][r] = 0.f;
#pragma unroll
        for (int kvb = 0; kvb < 2; ++kvb) {
          int r = kvb * 32 + l31;
#pragma unroll
          for (int ds = 0; ds < 8; ++ds) {
            int c = ds * 2 + hi;
            int cp = (c & 8) | ((c ^ r) & 7);
            bf16x8 kf = *(const bf16x8*)&Kt[cur][r * 128 + cp * 8];
            aS[kvb] = __builtin_amdgcn_mfma_f32_32x32x16_bf16(kf, qf[ds], aS[kvb], 0, 0, 0);
          }
        }
        const bool needmask = (j0 + 63 > qw);
        float mx = -3.0e38f;
#pragma unroll
        for (int a = 0; a < 2; ++a)
#pragma unroll
          for (int r = 0; r < 16; ++r) {
            float s = aS[a][r] * scale;
            if (needmask) {
              int kv = j0 + a * 32 + (r & 3) + 8 * (r >> 2) + 4 * hi;
              s = (kv > qrow) ? -3.0e38f : s;
            }
            aS[a][r] = s;
            mx = fmaxf(mx, s);
          }
        mx = fmaxf(mx, __shfl_xor(mx, 32));
        if (!__all(mx - m_r <= 8.0f)) {
          float mnew = fmaxf(m_r, mx);
          float corr = __builtin_amdgcn_exp2f((m_r - mnew) * L2E);
          l_r *= corr;
#pragma unroll
          for (int i = 0; i < 4; ++i)
#pragma unroll
            for (int r = 0; r < 16; ++r) accO[i][r] *= corr;
          m_r = mnew;
        }
        float sum = 0.f;
#pragma unroll
        for (int a = 0; a < 2; ++a)
#pragma unroll
          for (int r = 0; r < 16; ++r) {
            float pe = __builtin_amdgcn_exp2f((aS[a][r] - m_r) * L2E);
            aS[a][r] = pe;
            sum += pe;
          }
        sum += __shfl_xor(sum, 32);
        l_r += sum;

        u32 cc0[2][4], cc1[2][4];
#pragma unroll
        for (int a = 0; a < 2; ++a)
#pragma unroll
          for (int g = 0; g < 4; ++g) {
            cc0[a][g] = cvtpk(aS[a][g * 4 + 0], aS[a][g * 4 + 1]);
            cc1[a][g] = cvtpk(aS[a][g * 4 + 2], aS[a][g * 4 + 3]);
          }
        bf16x8 pa[4];
#pragma unroll
        for (int ks = 0; ks < 4; ++ks) {
          int a = ks >> 1, g0 = (ks & 1) * 2;
          u32 w0 = cc0[a][g0], w2 = cc0[a][g0 + 1];
          u32 w1 = cc1[a][g0], w3 = cc1[a][g0 + 1];
          plswap(w0, w2);
          plswap(w1, w3);
          u32x4 tv; tv.x = w0; tv.y = w1; tv.z = w2; tv.w = w3;
          pa[ks] = __builtin_bit_cast(bf16x8, tv);
        }
#pragma unroll
        for (int dblk = 0; dblk < 4; ++dblk) {
          int d = dblk * 32 + l31;
#pragma unroll
          for (int ks = 0; ks < 4; ++ks) {
            int c = ks * 2 + hi;
            int cp = c ^ (d & 7);
            bf16x8 vf = *(const bf16x8*)&Vt[cur][d * 64 + cp * 8];
            accO[dblk] = __builtin_amdgcn_mfma_f32_32x32x16_bf16(vf, pa[ks], accO[dblk], 0, 0, 0);
          }
        }
      }

      if (havenext) {
        u32x4 sv = __builtin_bit_cast(u32x4, (lane & 1) ? nv0 : nv1);
        u32x4 rv;
        rv.x = __shfl_xor(sv.x, 1); rv.y = __shfl_xor(sv.y, 1);
        rv.z = __shfl_xor(sv.z, 1); rv.w = __shfl_xor(sv.w, 1);
        bf16x8 recv = __builtin_bit_cast(bf16x8, rv);
        int kvp = lane >> 1;
#pragma unroll
        for (int i = 0; i < 8; ++i) {
          int d = w * 16 + (lane & 1) * 8 + i;
          u16 lo = (lane & 1) ? (u16)recv[i] : (u16)nv0[i];
          u16 hb = (lane & 1) ? (u16)nv1[i] : (u16)recv[i];
          u32 val = (u32)lo | ((u32)hb << 16);
          int cp = (kvp >> 2) ^ (d & 7);
          *(u32*)&Vt[cur ^ 1][d * 64 + cp * 8 + (kvp & 3) * 2] = val;
        }
      }
      __syncthreads();
    }

    {
      float il = 1.0f / l_r;
      size_t rb = ((size_t)b * Ss + qrow) * (size_t)(NHh * HDd) + (size_t)h * HDd;
#pragma unroll
      for (int dblk = 0; dblk < 4; ++dblk)
#pragma unroll
        for (int g = 0; g < 4; ++g) {
          int d0 = dblk * 32 + g * 8 + hi * 4;
          u64 pack = (u64)f2b(accO[dblk][g * 4 + 0] * il) |
                     ((u64)f2b(accO[dblk][g * 4 + 1] * il) << 16) |
                     ((u64)f2b(accO[dblk][g * 4 + 2] * il) << 32) |
                     ((u64)f2b(accO[dblk][g * 4 + 3] * il) << 48);
          *(u64*)&Ctx[rb + d0] = pack;
        }
    }
    __syncthreads();
  }
}

extern "C" void kernel_launch(void* const* d_in, const int* in_sizes, int n_in,
                              void* d_out, int out_size, void* d_ws, size_t ws_size,
                              hipStream_t stream) {
  const float* hidden = (const float*)d_in[0];
  const float* rope = (const float*)d_in[1];
  const float* Wqkv = (const float*)d_in[3];
  const float* bqkv = (const float*)d_in[4];
  const float* Wdense = (const float*)d_in[5];
  float* out = (float*)d_out;

  // ws layout: 104 MB total (L3-friendly).
  char* w = (char*)d_ws;
  u16* Xbf = (u16*)w;
  u16* ctx = Xbf;
  w += (size_t)33554432;
  u16* Wq = (u16*)w;
  u16* Wd = Wq;                        // alias: written AFTER QKV GEMM consumed Wq
  w += (size_t)37748736;
  u16* Qb = (u16*)w; w += (size_t)33554432;
  u16* Kb = (u16*)w; w += (size_t)2097152;
  u16* Vb = (u16*)w; w += (size_t)2097152;

  // 1. fused convert: hidden->Xbf, Wqkv->Wq
  cvt2_k<<<34816, 256, 0, stream>>>(hidden, Xbf, Wqkv, Wq);
  // 2. QKV GEMM (16x16x32, R15 form): 576 blocks; regions 8x9 per XCD
  gemm_qkv<4608, 4096, 9><<<dim3(576), 512, 0, stream>>>(
      Xbf, Wq, bqkv, Qb, Kb, Vb);
  // 3. RoPE on K only (Q's rope fused into attn_k)
  rope_k<<<(Bb * KVHh * Ss * 32 + 255) / 256, 256, 0, stream>>>(Kb, rope, KVHh);
  // 4. convert Wdense into Wq's region
  cvtW_k<<<16384, 256, 0, stream>>>(Wdense, Wd);
  // 5. flash attention (balanced causal pairing, fused Q-RoPE)
  attn_k<<<dim3(4, NHh, Bb), 512, 0, stream>>>(Qb, Kb, Vb, rope, ctx);
  // 6. dense GEMM: 256^2 4-quadrant schedule, 16x16x32 MFMA (R15 form); 256 blocks
  gemm_d256<<<dim3(256), 512, 0, stream>>>(ctx, Wd, out);
}

// Round 20
// 413.266 us; speedup vs baseline: 1.2182x; 1.1400x over previous
//
#include <hip/hip_runtime.h>
#include <hip/hip_bf16.h>
#include <stdint.h>

#define Bb 2
#define Ss 2048
#define Hh 4096
#define NHh 32
#define HDd 128
#define KVHh 2

typedef __attribute__((ext_vector_type(8))) short bf16x8;
typedef __attribute__((ext_vector_type(4))) float f32x4;
typedef __attribute__((ext_vector_type(16))) float f32x16;
typedef __attribute__((ext_vector_type(4))) unsigned int u32x4;
typedef unsigned short u16;
typedef unsigned int u32;
typedef unsigned long long u64;

__device__ __forceinline__ u16 f2b(float f) {
  union { float f; u32 u; } v; v.f = f;
  u32 r = v.u + 0x7fffu + ((v.u >> 16) & 1u);
  return (u16)(r >> 16);
}
__device__ __forceinline__ float b2f(u16 h) {
  union { u32 u; float f; } v; v.u = ((u32)h) << 16;
  return v.f;
}

__device__ __forceinline__ u32 cvtpk(float lo, float hi_) {
  u32 r;
  asm("v_cvt_pk_bf16_f32 %0, %1, %2" : "=v"(r) : "v"(lo), "v"(hi_));
  return r;
}
__device__ __forceinline__ void plswap(u32& x, u32& y) {
  asm volatile("v_permlane32_swap_b32 %0, %1" : "+v"(x), "+v"(y));
}

// async global->LDS, 16B per lane; LDS dest is wave-uniform base + lane*16
__device__ __forceinline__ void gload_lds16(const u16* g, u16* l) {
  __builtin_amdgcn_global_load_lds(
      (const __attribute__((address_space(1))) u32*)(uintptr_t)g,
      (__attribute__((address_space(3))) u32*)(u32)(uintptr_t)l,
      16, 0, 0);
}

// ---------------- fused f32 -> bf16 convert: hidden + Wqkv ----------------
__global__ void cvt2_k(const float* __restrict__ a, u16* __restrict__ oa,
                       const float* __restrict__ b, u16* __restrict__ ob) {
  int i = blockIdx.x * blockDim.x + threadIdx.x;
  const float* src;
  u16* dst;
  int off;
  if (i < 4194304) { src = a; dst = oa; off = i; }
  else { src = b; dst = ob; off = i - 4194304; }
  int idx = off * 4;
  float4 v = *(const float4*)&src[idx];
  u64 pack = (u64)f2b(v.x) | ((u64)f2b(v.y) << 16) |
             ((u64)f2b(v.z) << 32) | ((u64)f2b(v.w) << 48);
  *(u64*)&dst[idx] = pack;
}

// ---------------- f32 -> bf16 convert (Wdense, after QKV GEMM) ----------
__global__ void cvtW_k(const float* __restrict__ in, u16* __restrict__ out) {
  int i = blockIdx.x * blockDim.x + threadIdx.x;
  int idx = i * 4;
  float4 v = *(const float4*)&in[idx];
  u64 pack = (u64)f2b(v.x) | ((u64)f2b(v.y) << 16) |
             ((u64)f2b(v.z) << 32) | ((u64)f2b(v.w) << 48);
  *(u64*)&out[idx] = pack;
}

// ---------------- RoPE in-place on (B, nheads, S, HD) bf16 — K only ----------------
__global__ void rope_k(u16* __restrict__ X, const float* __restrict__ rope, int nheads) {
  int i = blockIdx.x * blockDim.x + threadIdx.x;
  int p = i & 31;
  int s = (i >> 5) & (Ss - 1);
  int bh = i >> 16;
  if (bh >= Bb * nheads) return;
  int b = bh / nheads;
  size_t base = ((size_t)bh * Ss + s) * HDd + p * 2;
  u32 x01 = *(u32*)&X[base];
  float x0 = b2f((u16)(x01 & 0xffff));
  float x1 = b2f((u16)(x01 >> 16));
  float2 rc = *(const float2*)&rope[(((size_t)b * Ss + s) * 32 + p) * 2];
  float o0 = x0 * rc.x - x1 * rc.y;
  float o1 = x1 * rc.x + x0 * rc.y;
  u32 o = (u32)f2b(o0) | ((u32)f2b(o1) << 16);
  *(u32*)&X[base] = o;
}

// ---------------- QKV GEMM: 256x256 d256 schedule + fused KV side-work --------------
// Q-part: exactly 4096x4096 -> 256 blocks, 1/CU, ZERO tail (the obstruction that
// kept QKV off the d256 schedule). KV (N=512, 12.5% extra FLOPs) fused: block
// (mtile,ntile) also computes KV cols [ntile*32,+32) for its 256 A-rows.
// B_kv staged 2-tiles-per-even-kt (8KB = 1 load/thread -> uniform vmcnt algebra).
// Boundary: vmcnt(5) even kt (leave B(kt+2)+Bkv), vmcnt(4) odd kt (force Bkv+
// B(kt+1)+A(kt+1) landed). KV reads+MFMAs in P1 (which had only 4 reads).
__global__ __launch_bounds__(512, 2) void gemm_qkv256(
    const u16* __restrict__ A, const u16* __restrict__ Bm,
    const float* __restrict__ bias,
    u16* __restrict__ Qb, u16* __restrict__ Kb, u16* __restrict__ Vb) {
  __shared__ u16 SM[2][4][8192];    // [buf][Bh0,Bh1,Ah0,Ah1][128x64 bf16] 128KB
  __shared__ u16 BKV[2][4096];      // [parity][2 tiles x 32 x 64]          16KB
  const int tid = threadIdx.x;
  const int wave = tid >> 6;
  const int lane = tid & 63;
  const int lr = lane & 15;
  const int lk = lane >> 4;
  const int wr = wave >> 2;          // 0..1 (M half)
  const int wc = wave & 3;           // 0..3 (N quarter; also KV row-group)
  const int bid = blockIdx.x;
  const int xcd = bid & 7;
  const int local = bid >> 3;
  const int m0 = ((xcd >> 2) * 8 + (local >> 2)) * 256;
  const int ntile = (xcd & 3) * 4 + (local & 3);
  const int n0 = ntile * 256;
  const int NT = 64;

  f32x4 acc[8][4];
#pragma unroll
  for (int i = 0; i < 8; ++i)
#pragma unroll
    for (int j = 0; j < 4; ++j) acc[i][j] = (f32x4){0.f, 0.f, 0.f, 0.f};
  f32x4 acckv[2][2];
#pragma unroll
  for (int i = 0; i < 2; ++i)
#pragma unroll
    for (int j = 0; j < 2; ++j) acckv[i][j] = (f32x4){0.f, 0.f, 0.f, 0.f};

  auto stage_half = [&](const u16* grows, int j, u16* dst) {
    if (j >= NT) return;
#pragma unroll
    for (int li = 0; li < 2; ++li) {
      int t16 = li * 512 + tid;
      int row = t16 >> 3, c = t16 & 7;
      int cs = c ^ (row & 7);
      gload_lds16(grows + (size_t)row * 4096 + j * 64 + cs * 8, dst + t16 * 8);
    }
  };
  const u16* Ah0g = A + (size_t)m0 * 4096;
  const u16* Ah1g = A + (size_t)(m0 + 128) * 4096;
  const u16* Bh0g = Bm + (size_t)n0 * 4096;
  const u16* Bh1g = Bm + (size_t)(n0 + 128) * 4096;
  const u16* KVg = Bm + (size_t)(4096 + ntile * 32) * 4096;

  // stage B_kv tiles j2, j2+1 (j2 even): 1 load/thread
  auto stage_bkv = [&](int j2) {
    if (j2 >= NT) return;
    int sub = tid >> 8;                // 0..1
    int idx = tid & 255;
    int row = idx >> 3, c = idx & 7;
    int cs = c ^ (row & 7);
    gload_lds16(KVg + (size_t)row * 4096 + (j2 + sub) * 64 + cs * 8,
                &BKV[(j2 >> 1) & 1][sub * 2048] + idx * 8);
  };

  stage_half(Ah0g, 0, &SM[0][2][0]);
  stage_half(Ah1g, 0, &SM[0][3][0]);
  stage_half(Bh0g, 0, &SM[0][0][0]);
  stage_half(Bh1g, 0, &SM[0][1][0]);
  stage_half(Bh0g, 1, &SM[1][0][0]);
  stage_half(Bh1g, 1, &SM[1][1][0]);
  stage_bkv(0);
  asm volatile("s_waitcnt vmcnt(0)");
  __builtin_amdgcn_s_barrier();
  __builtin_amdgcn_sched_barrier(0);

  for (int kt = 0; kt < NT; ++kt) {
    const int cur = kt & 1;
    const int nxt = cur ^ 1;
    const u16* Ahl = &SM[cur][2 + wr][0];
    const u16* Bhl = &SM[cur][wc >> 1][0];
    const u16* Bkvl = &BKV[(kt >> 1) & 1][(kt & 1) * 2048];
    const int rB0 = (wc & 1) * 64;
    auto rdA = [&](int r, int kk) {
      int ch = (kk * 4 + lk) ^ (r & 7);
      return *(const bf16x8*)&Ahl[r * 64 + ch * 8];
    };
    auto rdB = [&](int r, int kk) {
      int ch = (kk * 4 + lk) ^ (r & 7);
      return *(const bf16x8*)&Bhl[r * 64 + ch * 8];
    };
    auto rdBkv = [&](int r, int kk) {
      int ch = (kk * 4 + lk) ^ (r & 7);
      return *(const bf16x8*)&Bkvl[r * 64 + ch * 8];
    };

    bf16x8 bfr[4][2], af[2][2];
    // ---- P0: read B all (8) + A mi01 (4); stage A(kt+1) h0 ----
#pragma unroll
    for (int ni = 0; ni < 4; ++ni)
#pragma unroll
      for (int kk = 0; kk < 2; ++kk)
        bfr[ni][kk] = rdB(rB0 + ni * 16 + lr, kk);
#pragma unroll
    for (int i = 0; i < 2; ++i)
#pragma unroll
      for (int kk = 0; kk < 2; ++kk)
        af[i][kk] = rdA(i * 16 + lr, kk);
    stage_half(Ah0g, kt + 1, &SM[nxt][2][0]);
    __builtin_amdgcn_s_barrier();
    asm volatile("s_waitcnt lgkmcnt(0)");
    __builtin_amdgcn_sched_barrier(0);
    __builtin_amdgcn_s_setprio(1);
#pragma unroll
    for (int i = 0; i < 2; ++i)
#pragma unroll
      for (int ni = 0; ni < 4; ++ni)
#pragma unroll
        for (int kk = 0; kk < 2; ++kk)
          acc[i][ni] = __builtin_amdgcn_mfma_f32_16x16x32_bf16(af[i][kk], bfr[ni][kk], acc[i][ni], 0, 0, 0);
    __builtin_amdgcn_s_setprio(0);
    __builtin_amdgcn_s_barrier();

    // ---- P1: read A mi23 (4) + KV frags (8); stage A(kt+1) h1 + Bkv (even kt);
    //          MFMA: Q mi23 (16) + KV (8) ----
    {
      bf16x8 afkv[2][2], bfkv[2][2];
#pragma unroll
      for (int i = 0; i < 2; ++i)
#pragma unroll
        for (int kk = 0; kk < 2; ++kk)
          af[i][kk] = rdA((2 + i) * 16 + lr, kk);
#pragma unroll
      for (int rg = 0; rg < 2; ++rg)
#pragma unroll
        for (int kk = 0; kk < 2; ++kk)
          afkv[rg][kk] = rdA(wc * 32 + rg * 16 + lr, kk);
#pragma unroll
      for (int cg = 0; cg < 2; ++cg)
#pragma unroll
        for (int kk = 0; kk < 2; ++kk)
          bfkv[cg][kk] = rdBkv(cg * 16 + lr, kk);
      stage_half(Ah1g, kt + 1, &SM[nxt][3][0]);
      if ((kt & 1) == 0) stage_bkv(kt + 2);
      __builtin_amdgcn_s_barrier();
      asm volatile("s_waitcnt lgkmcnt(0)");
      __builtin_amdgcn_sched_barrier(0);
      __builtin_amdgcn_s_setprio(1);
#pragma unroll
      for (int i = 0; i < 2; ++i)
#pragma unroll
        for (int ni = 0; ni < 4; ++ni)
#pragma unroll
          for (int kk = 0; kk < 2; ++kk)
            acc[2 + i][ni] = __builtin_amdgcn_mfma_f32_16x16x32_bf16(af[i][kk], bfr[ni][kk], acc[2 + i][ni], 0, 0, 0);
#pragma unroll
      for (int rg = 0; rg < 2; ++rg)
#pragma unroll
        for (int cg = 0; cg < 2; ++cg)
#pragma unroll
          for (int kk = 0; kk < 2; ++kk)
            acckv[rg][cg] = __builtin_amdgcn_mfma_f32_16x16x32_bf16(afkv[rg][kk], bfkv[cg][kk], acckv[rg][cg], 0, 0, 0);
      __builtin_amdgcn_s_setprio(0);
      __builtin_amdgcn_s_barrier();
    }

    // ---- P2: read A mi45; stage B(kt+2) h0 (B reads done in P0) ----
#pragma unroll
    for (int i = 0; i < 2; ++i)
#pragma unroll
      for (int kk = 0; kk < 2; ++kk)
        af[i][kk] = rdA((4 + i) * 16 + lr, kk);
    stage_half(Bh0g, kt + 2, &SM[cur][0][0]);
    __builtin_amdgcn_s_barrier();
    asm volatile("s_waitcnt lgkmcnt(0)");
    __builtin_amdgcn_sched_barrier(0);
    __builtin_amdgcn_s_setprio(1);
#pragma unroll
    for (int i = 0; i < 2; ++i)
#pragma unroll
      for (int ni = 0; ni < 4; ++ni)
#pragma unroll
        for (int kk = 0; kk < 2; ++kk)
          acc[4 + i][ni] = __builtin_amdgcn_mfma_f32_16x16x32_bf16(af[i][kk], bfr[ni][kk], acc[4 + i][ni], 0, 0, 0);
    __builtin_amdgcn_s_setprio(0);
    __builtin_amdgcn_s_barrier();

    // ---- P3: read A mi67; stage B(kt+2) h1; parity-counted boundary vmcnt ----
#pragma unroll
    for (int i = 0; i < 2; ++i)
#pragma unroll
      for (int kk = 0; kk < 2; ++kk)
        af[i][kk] = rdA((6 + i) * 16 + lr, kk);
    stage_half(Bh1g, kt + 2, &SM[cur][1][0]);
    __builtin_amdgcn_s_barrier();
    asm volatile("s_waitcnt lgkmcnt(0)");
    __builtin_amdgcn_sched_barrier(0);
    __builtin_amdgcn_s_setprio(1);
#pragma unroll
    for (int i = 0; i < 2; ++i)
#pragma unroll
      for (int ni = 0; ni < 4; ++ni)
#pragma unroll
        for (int kk = 0; kk < 2; ++kk)
          acc[6 + i][ni] = __builtin_amdgcn_mfma_f32_16x16x32_bf16(af[i][kk], bfr[ni][kk], acc[6 + i][ni], 0, 0, 0);
    __builtin_amdgcn_s_setprio(0);
    if (kt < NT - 2) {
      if ((kt & 1) == 0) {
        asm volatile("s_waitcnt vmcnt(5)");   // leave B(kt+2)[4] + Bkv[1]
      } else {
        asm volatile("s_waitcnt vmcnt(4)");   // leave B(kt+2)[4]; Bkv forced landed
      }
    } else {
      asm volatile("s_waitcnt vmcnt(0)");
    }
    __builtin_amdgcn_s_barrier();
    __builtin_amdgcn_sched_barrier(0);
  }

  // epilogue: Q scatter (bias) — n always < 4096
#pragma unroll
  for (int ni = 0; ni < 4; ++ni) {
    int n = n0 + wc * 64 + ni * 16 + lr;
    float bv = bias[n];
#pragma unroll
    for (int mi = 0; mi < 8; ++mi) {
      int mb = m0 + wr * 128 + mi * 16 + lk * 4;
#pragma unroll
      for (int j = 0; j < 4; ++j) {
        int m = mb + j;
        int bb = m >> 11;
        int ss = m & 2047;
        u16 hv = f2b(acc[mi][ni][j] + bv);
        Qb[(((size_t)bb * NHh + (n >> 7)) * Ss + ss) * HDd + (n & 127)] = hv;
      }
    }
  }
  // epilogue: KV scatter (bias) — 32 cols per block, 32 rows per wave
#pragma unroll
  for (int rg = 0; rg < 2; ++rg)
#pragma unroll
    for (int cg = 0; cg < 2; ++cg) {
      int kvcol = ntile * 32 + cg * 16 + lr;      // 0..511
      float bv = bias[4096 + kvcol];
#pragma unroll
      for (int j = 0; j < 4; ++j) {
        int m = m0 + wr * 128 + wc * 32 + rg * 16 + lk * 4 + j;
        int bb = m >> 11;
        int ss = m & 2047;
        u16 hv = f2b(acckv[rg][cg][j] + bv);
        if (kvcol < 256) {
          Kb[(((size_t)bb * KVHh + (kvcol >> 7)) * Ss + ss) * HDd + (kvcol & 127)] = hv;
        } else {
          int i2 = kvcol - 256;
          Vb[(((size_t)bb * KVHh + (i2 >> 7)) * Ss + ss) * HDd + (i2 & 127)] = hv;
        }
      }
    }
}

// ---------------- dense GEMM: 256x256 tile, 4-quadrant schedule (R15 form) ----------
__global__ __launch_bounds__(512, 2) void gemm_d256(
    const u16* __restrict__ A, const u16* __restrict__ Bm,
    float* __restrict__ Cout) {
  __shared__ u16 SM[2][4][8192];
  const int tid = threadIdx.x;
  const int wave = tid >> 6;
  const int lane = tid & 63;
  const int lr = lane & 15;
  const int lk = lane >> 4;
  const int wr = wave >> 2;
  const int wc = wave & 3;
  const int bid = blockIdx.x;
  const int xcd = bid & 7;
  const int local = bid >> 3;
  const int m0 = ((xcd >> 2) * 8 + (local >> 2)) * 256;
  const int n0 = ((xcd & 3) * 4 + (local & 3)) * 256;
  const int NT = 64;

  f32x4 acc[8][4];
#pragma unroll
  for (int i = 0; i < 8; ++i)
#pragma unroll
    for (int j = 0; j < 4; ++j) acc[i][j] = (f32x4){0.f, 0.f, 0.f, 0.f};

  auto stage_half = [&](const u16* grows, int j, u16* dst) {
    if (j >= NT) return;
#pragma unroll
    for (int li = 0; li < 2; ++li) {
      int t16 = li * 512 + tid;
      int row = t16 >> 3, c = t16 & 7;
      int cs = c ^ (row & 7);
      gload_lds16(grows + (size_t)row * 4096 + j * 64 + cs * 8, dst + t16 * 8);
    }
  };
  const u16* Ah0g = A + (size_t)m0 * 4096;
  const u16* Ah1g = A + (size_t)(m0 + 128) * 4096;
  const u16* Bh0g = Bm + (size_t)n0 * 4096;
  const u16* Bh1g = Bm + (size_t)(n0 + 128) * 4096;

  stage_half(Ah0g, 0, &SM[0][2][0]);
  stage_half(Ah1g, 0, &SM[0][3][0]);
  stage_half(Bh0g, 0, &SM[0][0][0]);
  stage_half(Bh1g, 0, &SM[0][1][0]);
  stage_half(Bh0g, 1, &SM[1][0][0]);
  stage_half(Bh1g, 1, &SM[1][1][0]);
  asm volatile("s_waitcnt vmcnt(0)");
  __builtin_amdgcn_s_barrier();
  __builtin_amdgcn_sched_barrier(0);

  for (int kt = 0; kt < NT; ++kt) {
    const int cur = kt & 1;
    const int nxt = cur ^ 1;
    const u16* Ahl = &SM[cur][2 + wr][0];
    const u16* Bhl = &SM[cur][wc >> 1][0];
    const int rB0 = (wc & 1) * 64;
    auto rdA = [&](int r, int kk) {
      int ch = (kk * 4 + lk) ^ (r & 7);
      return *(const bf16x8*)&Ahl[r * 64 + ch * 8];
    };
    auto rdB = [&](int r, int kk) {
      int ch = (kk * 4 + lk) ^ (r & 7);
      return *(const bf16x8*)&Bhl[r * 64 + ch * 8];
    };

    bf16x8 bfr[4][2], af[2][2];
#pragma unroll
    for (int ni = 0; ni < 4; ++ni)
#pragma unroll
      for (int kk = 0; kk < 2; ++kk)
        bfr[ni][kk] = rdB(rB0 + ni * 16 + lr, kk);
#pragma unroll
    for (int i = 0; i < 2; ++i)
#pragma unroll
      for (int kk = 0; kk < 2; ++kk)
        af[i][kk] = rdA(i * 16 + lr, kk);
    stage_half(Ah0g, kt + 1, &SM[nxt][2][0]);
    __builtin_amdgcn_s_barrier();
    asm volatile("s_waitcnt lgkmcnt(0)");
    __builtin_amdgcn_sched_barrier(0);
    __builtin_amdgcn_s_setprio(1);
#pragma unroll
    for (int i = 0; i < 2; ++i)
#pragma unroll
      for (int ni = 0; ni < 4; ++ni)
#pragma unroll
        for (int kk = 0; kk < 2; ++kk)
          acc[i][ni] = __builtin_amdgcn_mfma_f32_16x16x32_bf16(af[i][kk], bfr[ni][kk], acc[i][ni], 0, 0, 0);
    __builtin_amdgcn_s_setprio(0);
    __builtin_amdgcn_s_barrier();

#pragma unroll
    for (int i = 0; i < 2; ++i)
#pragma unroll
      for (int kk = 0; kk < 2; ++kk)
        af[i][kk] = rdA((2 + i) * 16 + lr, kk);
    stage_half(Ah1g, kt + 1, &SM[nxt][3][0]);
    __builtin_amdgcn_s_barrier();
    asm volatile("s_waitcnt lgkmcnt(0)");
    __builtin_amdgcn_sched_barrier(0);
    __builtin_amdgcn_s_setprio(1);
#pragma unroll
    for (int i = 0; i < 2; ++i)
#pragma unroll
      for (int ni = 0; ni < 4; ++ni)
#pragma unroll
        for (int kk = 0; kk < 2; ++kk)
          acc[2 + i][ni] = __builtin_amdgcn_mfma_f32_16x16x32_bf16(af[i][kk], bfr[ni][kk], acc[2 + i][ni], 0, 0, 0);
    __builtin_amdgcn_s_setprio(0);
    __builtin_amdgcn_s_barrier();

#pragma unroll
    for (int i = 0; i < 2; ++i)
#pragma unroll
      for (int kk = 0; kk < 2; ++kk)
        af[i][kk] = rdA((4 + i) * 16 + lr, kk);
    stage_half(Bh0g, kt + 2, &SM[cur][0][0]);
    __builtin_amdgcn_s_barrier();
    asm volatile("s_waitcnt lgkmcnt(0)");
    __builtin_amdgcn_sched_barrier(0);
    __builtin_amdgcn_s_setprio(1);
#pragma unroll
    for (int i = 0; i < 2; ++i)
#pragma unroll
      for (int ni = 0; ni < 4; ++ni)
#pragma unroll
        for (int kk = 0; kk < 2; ++kk)
          acc[4 + i][ni] = __builtin_amdgcn_mfma_f32_16x16x32_bf16(af[i][kk], bfr[ni][kk], acc[4 + i][ni], 0, 0, 0);
    __builtin_amdgcn_s_setprio(0);
    __builtin_amdgcn_s_barrier();

#pragma unroll
    for (int i = 0; i < 2; ++i)
#pragma unroll
      for (int kk = 0; kk < 2; ++kk)
        af[i][kk] = rdA((6 + i) * 16 + lr, kk);
    stage_half(Bh1g, kt + 2, &SM[cur][1][0]);
    __builtin_amdgcn_s_barrier();
    asm volatile("s_waitcnt lgkmcnt(0)");
    __builtin_amdgcn_sched_barrier(0);
    __builtin_amdgcn_s_setprio(1);
#pragma unroll
    for (int i = 0; i < 2; ++i)
#pragma unroll
      for (int ni = 0; ni < 4; ++ni)
#pragma unroll
        for (int kk = 0; kk < 2; ++kk)
          acc[6 + i][ni] = __builtin_amdgcn_mfma_f32_16x16x32_bf16(af[i][kk], bfr[ni][kk], acc[6 + i][ni], 0, 0, 0);
    __builtin_amdgcn_s_setprio(0);
    if (kt < NT - 2) {
      asm volatile("s_waitcnt vmcnt(4)");
    } else {
      asm volatile("s_waitcnt vmcnt(0)");
    }
    __builtin_amdgcn_s_barrier();
    __builtin_amdgcn_sched_barrier(0);
  }

#pragma unroll
  for (int mi = 0; mi < 8; ++mi)
#pragma unroll
    for (int ni = 0; ni < 4; ++ni) {
      int col = n0 + wc * 64 + ni * 16 + lr;
      int rowb = m0 + wr * 128 + mi * 16 + lk * 4;
#pragma unroll
      for (int j = 0; j < 4; ++j)
        Cout[(size_t)(rowb + j) * 4096 + col] = acc[mi][ni][j];
    }
}

// ---------------- causal GQA flash attention, 8-wave 32x32 swapped-QK^T ----------------
__global__ __launch_bounds__(512, 2) void attn_k(
    const u16* __restrict__ Qb, const u16* __restrict__ Kb,
    const u16* __restrict__ Vb, const float* __restrict__ rope,
    u16* __restrict__ Ctx) {
  __shared__ u16 Kt[2][64 * 128];
  __shared__ u16 Vt[2][128 * 64];
  const int tid = threadIdx.x;
  const int w = tid >> 6;
  const int lane = tid & 63;
  const int l31 = lane & 31;
  const int hi = lane >> 5;
  const int h = blockIdx.y, b = blockIdx.z;
  const int hkv = h >> 4;
  const u16* Qp = Qb + ((size_t)(b * NHh + h)) * Ss * HDd;
  const u16* Kp = Kb + ((size_t)(b * KVHh + hkv)) * Ss * HDd;
  const u16* Vp = Vb + ((size_t)(b * KVHh + hkv)) * Ss * HDd;

  const float scale = 0.08838834764831845f;
  const float L2E = 1.4426950408889634f;

  for (int hp = 0; hp < 2; ++hp) {
    const int qt = hp == 0 ? (7 - (int)blockIdx.x) : (int)blockIdx.x;
    const int qs = qt * 256;
    const int qw = qs + w * 32;
    const int qrow = qw + l31;
    const int nt = qs / 64 + 4;

    bf16x8 qf[8];
#pragma unroll
    for (int ds = 0; ds < 8; ++ds)
      qf[ds] = *(const bf16x8*)&Qp[(size_t)qrow * HDd + ds * 16 + hi * 8];
#pragma unroll
    for (int ds = 0; ds < 4; ++ds) {
      bf16x8 q = qf[ds];
      bf16x8 o;
#pragma unroll
      for (int i = 0; i < 4; ++i) {
        int p = ds * 8 + hi * 4 + i;
        float2 rc = *(const float2*)&rope[(((size_t)b * Ss + qrow) * 32 + p) * 2];
        float x0 = b2f((u16)q[2 * i]), x1 = b2f((u16)q[2 * i + 1]);
        o[2 * i] = (short)f2b(x0 * rc.x - x1 * rc.y);
        o[2 * i + 1] = (short)f2b(x1 * rc.x + x0 * rc.y);
      }
      qf[ds] = o;
    }

    f32x16 accO[4];
#pragma unroll
    for (int i = 0; i < 4; ++i)
#pragma unroll
      for (int r = 0; r < 16; ++r) accO[i][r] = 0.f;
    float m_r = -3.0e38f, l_r = 0.f;

    {
#pragma unroll
      for (int i = 0; i < 2; ++i) {
        int slot = w * 2 + i;
        int r = slot * 4 + (lane >> 4);
        int p = lane & 15;
        int gc = (p & 8) | ((p ^ r) & 7);
        gload_lds16(Kp + (size_t)r * HDd + gc * 8, &Kt[0][slot * 512]);
      }
      bf16x8 v0 = *(const bf16x8*)&Vp[(size_t)lane * HDd + w * 16];
      bf16x8 v1 = *(const bf16x8*)&Vp[(size_t)lane * HDd + w * 16 + 8];
      u32x4 sv = __builtin_bit_cast(u32x4, (lane & 1) ? v0 : v1);
      u32x4 rv;
      rv.x = __shfl_xor(sv.x, 1); rv.y = __shfl_xor(sv.y, 1);
      rv.z = __shfl_xor(sv.z, 1); rv.w = __shfl_xor(sv.w, 1);
      bf16x8 recv = __builtin_bit_cast(bf16x8, rv);
      int kvp = lane >> 1;
#pragma unroll
      for (int i = 0; i < 8; ++i) {
        int d = w * 16 + (lane & 1) * 8 + i;
        u16 lo = (lane & 1) ? (u16)recv[i] : (u16)v0[i];
        u16 hb = (lane & 1) ? (u16)v1[i] : (u16)recv[i];
        u32 val = (u32)lo | ((u32)hb << 16);
        int cp = (kvp >> 2) ^ (d & 7);
        *(u32*)&Vt[0][d * 64 + cp * 8 + (kvp & 3) * 2] = val;
      }
    }
    __syncthreads();

    for (int t = 0; t < nt; ++t) {
      const int j0 = t * 64;
      const int cur = t & 1;
      const bool havenext = (t + 1 < nt);
      bf16x8 nv0, nv1;
      if (havenext) {
        const int j1 = j0 + 64;
#pragma unroll
        for (int i = 0; i < 2; ++i) {
          int slot = w * 2 + i;
          int r = slot * 4 + (lane >> 4);
          int p = lane & 15;
          int gc = (p & 8) | ((p ^ r) & 7);
          gload_lds16(Kp + (size_t)(j1 + r) * HDd + gc * 8, &Kt[cur ^ 1][slot * 512]);
        }
        nv0 = *(const bf16x8*)&Vp[(size_t)(j1 + lane) * HDd + w * 16];
        nv1 = *(const bf16x8*)&Vp[(size_t)(j1 + lane) * HDd + w * 16 + 8];
      }

      if (j0 <= qw + 31) {
        f32x16 aS[2];
#pragma unroll
        for (int a = 0; a < 2; ++a)
#pragma unroll
          for (int r = 0; r < 16; ++r) aS[a][r] = 0.f;
#pragma unroll
        for (int kvb = 0; kvb < 2; ++kvb) {
          int r = kvb * 32 + l31;
#pragma unroll
          for (int ds = 0; ds < 8; ++ds) {
            int c = ds * 2 + hi;
            int cp = (c & 8) | ((c ^ r) & 7);
            bf16x8 kf = *(const bf16x8*)&Kt[cur][r * 128 + cp * 8];
            aS[kvb] = __builtin_amdgcn_mfma_f32_32x32x16_bf16(kf, qf[ds], aS[kvb], 0, 0, 0);
          }
        }
        const bool needmask = (j0 + 63 > qw);
        float mx = -3.0e38f;
#pragma unroll
        for (int a = 0; a < 2; ++a)
#pragma unroll
          for (int r = 0; r < 16; ++r) {
            float s = aS[a][r] * scale;
            if (needmask) {
              int kv = j0 + a * 32 + (r & 3) + 8 * (r >> 2) + 4 * hi;
              s = (kv > qrow) ? -3.0e38f : s;
            }
            aS[a][r] = s;
            mx = fmaxf(mx, s);
          }
        mx = fmaxf(mx, __shfl_xor(mx, 32));
        if (!__all(mx - m_r <= 8.0f)) {
          float mnew = fmaxf(m_r, mx);
          float corr = __builtin_amdgcn_exp2f((m_r - mnew) * L2E);
          l_r *= corr;
#pragma unroll
          for (int i = 0; i < 4; ++i)
#pragma unroll
            for (int r = 0; r < 16; ++r) accO[i][r] *= corr;
          m_r = mnew;
        }
        float sum = 0.f;
#pragma unroll
        for (int a = 0; a < 2; ++a)
#pragma unroll
          for (int r = 0; r < 16; ++r) {
            float pe = __builtin_amdgcn_exp2f((aS[a][r] - m_r) * L2E);
            aS[a][r] = pe;
            sum += pe;
          }
        sum += __shfl_xor(sum, 32);
        l_r += sum;

        u32 cc0[2][4], cc1[2][4];
#pragma unroll
        for (int a = 0; a < 2; ++a)
#pragma unroll
          for (int g = 0; g < 4; ++g) {
            cc0[a][g] = cvtpk(aS[a][g * 4 + 0], aS[a][g * 4 + 1]);
            cc1[a][g] = cvtpk(aS[a][g * 4 + 2], aS[a][g * 4 + 3]);
          }
        bf16x8 pa[4];
#pragma unroll
        for (int ks = 0; ks < 4; ++ks) {
          int a = ks >> 1, g0 = (ks & 1) * 2;
          u32 w0 = cc0[a][g0], w2 = cc0[a][g0 + 1];
          u32 w1 = cc1[a][g0], w3 = cc1[a][g0 + 1];
          plswap(w0, w2);
          plswap(w1, w3);
          u32x4 tv; tv.x = w0; tv.y = w1; tv.z = w2; tv.w = w3;
          pa[ks] = __builtin_bit_cast(bf16x8, tv);
        }
#pragma unroll
        for (int dblk = 0; dblk < 4; ++dblk) {
          int d = dblk * 32 + l31;
#pragma unroll
          for (int ks = 0; ks < 4; ++ks) {
            int c = ks * 2 + hi;
            int cp = c ^ (d & 7);
            bf16x8 vf = *(const bf16x8*)&Vt[cur][d * 64 + cp * 8];
            accO[dblk] = __builtin_amdgcn_mfma_f32_32x32x16_bf16(vf, pa[ks], accO[dblk], 0, 0, 0);
          }
        }
      }

      if (havenext) {
        u32x4 sv = __builtin_bit_cast(u32x4, (lane & 1) ? nv0 : nv1);
        u32x4 rv;
        rv.x = __shfl_xor(sv.x, 1); rv.y = __shfl_xor(sv.y, 1);
        rv.z = __shfl_xor(sv.z, 1); rv.w = __shfl_xor(sv.w, 1);
        bf16x8 recv = __builtin_bit_cast(bf16x8, rv);
        int kvp = lane >> 1;
#pragma unroll
        for (int i = 0; i < 8; ++i) {
          int d = w * 16 + (lane & 1) * 8 + i;
          u16 lo = (lane & 1) ? (u16)recv[i] : (u16)nv0[i];
          u16 hb = (lane & 1) ? (u16)nv1[i] : (u16)recv[i];
          u32 val = (u32)lo | ((u32)hb << 16);
          int cp = (kvp >> 2) ^ (d & 7);
          *(u32*)&Vt[cur ^ 1][d * 64 + cp * 8 + (kvp & 3) * 2] = val;
        }
      }
      __syncthreads();
    }

    {
      float il = 1.0f / l_r;
      size_t rb = ((size_t)b * Ss + qrow) * (size_t)(NHh * HDd) + (size_t)h * HDd;
#pragma unroll
      for (int dblk = 0; dblk < 4; ++dblk)
#pragma unroll
        for (int g = 0; g < 4; ++g) {
          int d0 = dblk * 32 + g * 8 + hi * 4;
          u64 pack = (u64)f2b(accO[dblk][g * 4 + 0] * il) |
                     ((u64)f2b(accO[dblk][g * 4 + 1] * il) << 16) |
                     ((u64)f2b(accO[dblk][g * 4 + 2] * il) << 32) |
                     ((u64)f2b(accO[dblk][g * 4 + 3] * il) << 48);
          *(u64*)&Ctx[rb + d0] = pack;
        }
    }
    __syncthreads();
  }
}

extern "C" void kernel_launch(void* const* d_in, const int* in_sizes, int n_in,
                              void* d_out, int out_size, void* d_ws, size_t ws_size,
                              hipStream_t stream) {
  const float* hidden = (const float*)d_in[0];
  const float* rope = (const float*)d_in[1];
  const float* Wqkv = (const float*)d_in[3];
  const float* bqkv = (const float*)d_in[4];
  const float* Wdense = (const float*)d_in[5];
  float* out = (float*)d_out;

  // ws layout: 104 MB total (L3-friendly).
  char* w = (char*)d_ws;
  u16* Xbf = (u16*)w;
  u16* ctx = Xbf;
  w += (size_t)33554432;
  u16* Wq = (u16*)w;
  u16* Wd = Wq;                        // alias: written AFTER QKV GEMM consumed Wq
  w += (size_t)37748736;
  u16* Qb = (u16*)w; w += (size_t)33554432;
  u16* Kb = (u16*)w; w += (size_t)2097152;
  u16* Vb = (u16*)w; w += (size_t)2097152;

  // 1. fused convert: hidden->Xbf, Wqkv->Wq
  cvt2_k<<<34816, 256, 0, stream>>>(hidden, Xbf, Wqkv, Wq);
  // 2. QKV GEMM: d256 schedule + fused KV side-work; 256 blocks, 1/CU, no tail
  gemm_qkv256<<<dim3(256), 512, 0, stream>>>(Xbf, Wq, bqkv, Qb, Kb, Vb);
  // 3. RoPE on K only (Q's rope fused into attn_k)
  rope_k<<<(Bb * KVHh * Ss * 32 + 255) / 256, 256, 0, stream>>>(Kb, rope, KVHh);
  // 4. convert Wdense into Wq's region
  cvtW_k<<<16384, 256, 0, stream>>>(Wdense, Wd);
  // 5. flash attention (balanced causal pairing, fused Q-RoPE)
  attn_k<<<dim3(4, NHh, Bb), 512, 0, stream>>>(Qb, Kb, Vb, rope, ctx);
  // 6. dense GEMM: 256^2 4-quadrant schedule; 256 blocks (1/CU)
  gemm_d256<<<dim3(256), 512, 0, stream>>>(ctx, Wd, out);
}